// Round 11
// baseline (362.875 us; speedup 1.0000x reference)
//
#include <hip/hip_runtime.h>
#include <hip/hip_bf16.h>

#define NNODES 100000
#define HID 256
#define NMOVES 500000
#define NGRAPHS 512
#define BM 128
#define BN 32
#define PB 128   // partial-reduction blocks

typedef __attribute__((ext_vector_type(8))) short short8;
typedef __attribute__((ext_vector_type(4))) float f32x4;

#define AS_GLOBAL __attribute__((address_space(1)))
#define AS_LDS __attribute__((address_space(3)))

__device__ __forceinline__ unsigned f2bf(float f) {
    unsigned u = __builtin_bit_cast(unsigned, f);
    u += 0x7FFFu + ((u >> 16) & 1u);   // round-to-nearest-even
    return u >> 16;
}
__device__ __forceinline__ float bf2f(ushort h) {
    unsigned u = ((unsigned)h) << 16;
    return __builtin_bit_cast(float, u);
}
// order-preserving float<->uint encoding for max
__device__ __forceinline__ unsigned encf(float f) {
    unsigned b = __builtin_bit_cast(unsigned, f);
    return (b & 0x80000000u) ? ~b : (b ^ 0x80000000u);
}
__device__ __forceinline__ float decf(unsigned u) {
    unsigned b = (u & 0x80000000u) ? (u ^ 0x80000000u) : ~u;
    return __builtin_bit_cast(float, b);
}

// ---- build W1' transposed: W1t[n][k] ----
__global__ void k_convert_w1(const float* __restrict__ W1, ushort* __restrict__ W1t) {
    int t = blockIdx.x * blockDim.x + threadIdx.x; // 131072
    int n = t >> 8, k = t & 255;
    float v = (n < 256) ? W1[k * 256 + n] : W1[(k + 256) * 256 + (n - 256)];
    W1t[t] = (ushort)f2bf(v);
}

// ---- GEMM v4: R9 pipeline + R10 A-path + packed epilogue, 32KB LDS ----
// A fragments: direct global f32 loads, converted to bf16 in-register (no A
// LDS phase). B: shared double-buffered BN=32 strips in 32KB LDS, staged via
// gload_lds w=16 with pre-swizzled source. Counted vmcnt: steady window =
// stores(2) + next stage(2) -> vmcnt(4); last strip vmcnt(2). 4 blocks/CU.
// Swapped-operand MFMA (R7/R10-verified): reg j = P-col -> packed uint2.
__global__ __launch_bounds__(512, 8) void k_gemm(const float* __restrict__ emb,
                                                 const ushort* __restrict__ Bt,
                                                 ushort* __restrict__ P, int M) {
    __shared__ __align__(16) char lds[32768];   // 2 x 16KB B buffers
    int tid = threadIdx.x;
    int lane = tid & 63;
    int wave = tid >> 6;
    int tm = blockIdx.x * BM;
    int wm = wave >> 1;   // 0..3  (32-row group)
    int wn = wave & 1;    // 0..1  (16-col group within strip)
    int fr = lane & 15;
    int q = lane >> 4;    // 0..3
    int sw = fr & 7;

    // stage strip: 16KB = 512 thr x 2 x 16B; pre-swizzled source
#define STAGE(STRIP, BUFI)                                                          \
    {                                                                               \
        _Pragma("unroll")                                                           \
        for (int i = 0; i < 2; ++i) {                                               \
            int cid = i * 512 + tid;       /* 16B chunk 0..1023 */                  \
            int row = cid >> 5, c = cid & 31;                                       \
            const ushort* src = Bt + (size_t)((STRIP) * BN + row) * 256             \
                                   + ((c ^ (row & 7)) << 3);                        \
            __builtin_amdgcn_global_load_lds((const AS_GLOBAL void*)src,            \
                (AS_LDS void*)(lds + (BUFI) * 16384 + (i * 512 + wave * 64) * 16),  \
                16, 0, 0);                                                          \
        }                                                                           \
    }

    STAGE(0, 0);
    STAGE(1, 1);

    // ---- A fragments straight from global (f32 -> bf16 in-register) ----
    short8 af[2][8];
#pragma unroll
    for (int m = 0; m < 2; ++m) {
        int grow = tm + wm * 32 + m * 16 + fr;
        if (grow >= M) grow = M - 1;
        const float* base = emb + (size_t)grow * 256;
#pragma unroll
        for (int kt = 0; kt < 8; ++kt) {
            float4 v0 = *reinterpret_cast<const float4*>(base + (kt * 4 + q) * 8);
            float4 v1 = *reinterpret_cast<const float4*>(base + (kt * 4 + q) * 8 + 4);
            short8 f;
            f[0] = (short)f2bf(v0.x); f[1] = (short)f2bf(v0.y);
            f[2] = (short)f2bf(v0.z); f[3] = (short)f2bf(v0.w);
            f[4] = (short)f2bf(v1.x); f[5] = (short)f2bf(v1.y);
            f[6] = (short)f2bf(v1.z); f[7] = (short)f2bf(v1.w);
            af[m][kt] = f;
        }
    }

#pragma unroll 1
    for (int r = 0; r < 16; ++r) {
        // wait for stage(r); FIFO leaves stores(r-1)[2] + stage(r+1)[2]
        if (r < 15) asm volatile("s_waitcnt vmcnt(4)" ::: "memory");
        else        asm volatile("s_waitcnt vmcnt(2)" ::: "memory");
        asm volatile("s_barrier" ::: "memory");

        const char* bp = lds + (r & 1) * 16384;
        f32x4 acc0 = {0.f, 0.f, 0.f, 0.f};
        f32x4 acc1 = {0.f, 0.f, 0.f, 0.f};
#pragma unroll
        for (int kt = 0; kt < 8; ++kt) {
            short8 bf = *reinterpret_cast<const short8*>(
                bp + (wn * 16 + fr) * 512 + (((kt * 4 + q) ^ sw) << 4));
            acc0 = __builtin_amdgcn_mfma_f32_16x16x32_bf16(bf, af[0][kt], acc0, 0, 0, 0);
            acc1 = __builtin_amdgcn_mfma_f32_16x16x32_bf16(bf, af[1][kt], acc1, 0, 0, 0);
        }
        // packed epilogue: lane fr = P-row, regs = 4 consecutive P-cols
        int pcol = r * BN + wn * 16 + q * 4;
        int prow0 = tm + wm * 32 + fr;
        if (prow0 < M) {
            uint2 pk;
            pk.x = f2bf(acc0[0]) | (f2bf(acc0[1]) << 16);
            pk.y = f2bf(acc0[2]) | (f2bf(acc0[3]) << 16);
            *reinterpret_cast<uint2*>(P + (size_t)prow0 * 512 + pcol) = pk;
        }
        int prow1 = prow0 + 16;
        if (prow1 < M) {
            uint2 pk;
            pk.x = f2bf(acc1[0]) | (f2bf(acc1[1]) << 16);
            pk.y = f2bf(acc1[2]) | (f2bf(acc1[3]) << 16);
            *reinterpret_cast<uint2*>(P + (size_t)prow1 * 512 + pcol) = pk;
        }

        asm volatile("s_barrier" ::: "memory");   // all waves done reading buf
        if (r < 14) STAGE(r + 2, (r & 1));
    }
#undef STAGE
}

// ---- per-move MLP tail: 16 lanes/move, 4 moves/wave, unroll x2. NO atomics ----
__device__ __forceinline__ float dot8(uint4 a, uint4 b, const float* b1v, const float* w2v, int o) {
    unsigned aw[4] = {a.x, a.y, a.z, a.w};
    unsigned bw[4] = {b.x, b.y, b.z, b.w};
    float r = 0.f;
#pragma unroll
    for (int i = 0; i < 4; ++i) {
        float a0 = bf2f((ushort)(aw[i] & 0xffffu));
        float a1 = bf2f((ushort)(aw[i] >> 16));
        float c0 = bf2f((ushort)(bw[i] & 0xffffu));
        float c1 = bf2f((ushort)(bw[i] >> 16));
        float h0 = fmaxf(a0 + c0 + b1v[o + 2 * i], 0.f);
        float h1 = fmaxf(a1 + c1 + b1v[o + 2 * i + 1], 0.f);
        r += h0 * w2v[o + 2 * i] + h1 * w2v[o + 2 * i + 1];
    }
    return r;
}

__global__ __launch_bounds__(256) void k_moves(const int* __restrict__ srcs,
                                               const int* __restrict__ tgts,
                                               const int* __restrict__ batch,
                                               const ushort* __restrict__ P,
                                               const float* __restrict__ b1,
                                               const float* __restrict__ W2,
                                               const float* __restrict__ b2,
                                               float* __restrict__ logits,
                                               int* __restrict__ mb) {
    int tid = threadIdx.x;
    int lane = tid & 63;
    int sub = lane >> 4;
    int ch = lane & 15;

    float b1v[16], w2v[16];
    const float4* b1p = reinterpret_cast<const float4*>(b1);
    const float4* w2p = reinterpret_cast<const float4*>(W2);
#pragma unroll
    for (int q = 0; q < 4; ++q) {
        float4 bv = b1p[ch * 4 + q];
        float4 wv = w2p[ch * 4 + q];
        b1v[q * 4 + 0] = bv.x; b1v[q * 4 + 1] = bv.y; b1v[q * 4 + 2] = bv.z; b1v[q * 4 + 3] = bv.w;
        w2v[q * 4 + 0] = wv.x; w2v[q * 4 + 1] = wv.y; w2v[q * 4 + 2] = wv.z; w2v[q * 4 + 3] = wv.w;
    }
    float b2s = b2[0];

    int wid = (blockIdx.x * 256 + tid) >> 6;
    int nw = (gridDim.x * 256) >> 6;

    for (int base = wid * 8; base < NMOVES; base += nw * 8) {
        int m0 = base + sub;
        int m1 = base + 4 + sub;
        int s0 = srcs[m0], t0 = tgts[m0];
        int s1 = srcs[m1], t1 = tgts[m1];
        const uint4* pa0 = reinterpret_cast<const uint4*>(P + (size_t)s0 * 512 + ch * 16);
        const uint4* pb0 = reinterpret_cast<const uint4*>(P + (size_t)t0 * 512 + 256 + ch * 16);
        const uint4* pa1 = reinterpret_cast<const uint4*>(P + (size_t)s1 * 512 + ch * 16);
        const uint4* pb1 = reinterpret_cast<const uint4*>(P + (size_t)t1 * 512 + 256 + ch * 16);
        uint4 a00 = pa0[0], a01 = pa0[1];
        uint4 c00 = pb0[0], c01 = pb0[1];
        uint4 a10 = pa1[0], a11 = pa1[1];
        uint4 c10 = pb1[0], c11 = pb1[1];
        int g0 = batch[s0];
        int g1 = batch[s1];

        float p0 = dot8(a00, c00, b1v, w2v, 0) + dot8(a01, c01, b1v, w2v, 8);
        float p1 = dot8(a10, c10, b1v, w2v, 0) + dot8(a11, c11, b1v, w2v, 8);
#pragma unroll
        for (int off = 1; off < 16; off <<= 1) {
            p0 += __shfl_xor(p0, off);
            p1 += __shfl_xor(p1, off);
        }
        if (ch == 0) {
            logits[m0] = p0 + b2s; mb[m0] = g0;
            logits[m1] = p1 + b2s; mb[m1] = g1;
        }
    }
}

// ---- per-block segment partials (vectorized 4 moves/thread) ----
__global__ __launch_bounds__(256) void k_part(const float* __restrict__ logits,
                                              const int* __restrict__ mb,
                                              float* __restrict__ pmax,
                                              float* __restrict__ psum) {
    __shared__ unsigned lmax[NGRAPHS];
    __shared__ float lsum[NGRAPHS];
    int tid = threadIdx.x;
    lmax[tid] = 0u; lmax[tid + 256] = 0u;
    lsum[tid] = 0.f; lsum[tid + 256] = 0.f;
    __syncthreads();

    const int NV = NMOVES / 4;
    int stride = PB * 256;
    for (int v = blockIdx.x * 256 + tid; v < NV; v += stride) {
        float4 l = reinterpret_cast<const float4*>(logits)[v];
        int4 g = reinterpret_cast<const int4*>(mb)[v];
        atomicMax(&lmax[g.x], encf(l.x));
        atomicMax(&lmax[g.y], encf(l.y));
        atomicMax(&lmax[g.z], encf(l.z));
        atomicMax(&lmax[g.w], encf(l.w));
    }
    __syncthreads();
    for (int v = blockIdx.x * 256 + tid; v < NV; v += stride) {
        float4 l = reinterpret_cast<const float4*>(logits)[v];
        int4 g = reinterpret_cast<const int4*>(mb)[v];
        atomicAdd(&lsum[g.x], __expf(l.x - decf(lmax[g.x])));
        atomicAdd(&lsum[g.y], __expf(l.y - decf(lmax[g.y])));
        atomicAdd(&lsum[g.z], __expf(l.z - decf(lmax[g.z])));
        atomicAdd(&lsum[g.w], __expf(l.w - decf(lmax[g.w])));
    }
    __syncthreads();

#pragma unroll
    for (int i = 0; i < 2; ++i) {
        int s = tid + i * 256;
        unsigned e = lmax[s];
        pmax[blockIdx.x * NGRAPHS + s] = (e == 0u) ? -INFINITY : decf(e);
        psum[blockIdx.x * NGRAPHS + s] = lsum[s];
    }
}

// ---- fold PB partials per segment: one block per segment, wave-parallel ----
__global__ __launch_bounds__(64) void k_combine(const float* __restrict__ pmax,
                                                const float* __restrict__ psum,
                                                float* __restrict__ gmax,
                                                float* __restrict__ ginv) {
    int s = blockIdx.x;      // segment 0..511
    int lane = threadIdx.x;  // 0..63
    float pm0 = pmax[lane * NGRAPHS + s];
    float pm1 = pmax[(lane + 64) * NGRAPHS + s];
    float ps0 = psum[lane * NGRAPHS + s];
    float ps1 = psum[(lane + 64) * NGRAPHS + s];
    float M = fmaxf(pm0, pm1);
#pragma unroll
    for (int off = 32; off; off >>= 1) M = fmaxf(M, __shfl_xor(M, off));
    float S = (ps0 > 0.f ? ps0 * __expf(pm0 - M) : 0.f)
            + (ps1 > 0.f ? ps1 * __expf(pm1 - M) : 0.f);
#pragma unroll
    for (int off = 32; off; off >>= 1) S += __shfl_xor(S, off);
    if (lane == 0) {
        gmax[s] = M;
        ginv[s] = 1.f / (S + 1e-16f);
    }
}

// ---- normalize (vectorized 4 moves/thread) ----
__global__ void k_norm(const float* __restrict__ logits, const int* __restrict__ mb,
                       const float* __restrict__ gmax, const float* __restrict__ ginv,
                       float* __restrict__ out) {
    const int NV = NMOVES / 4;
    int i = blockIdx.x * blockDim.x + threadIdx.x;
    int n = gridDim.x * blockDim.x;
    for (int v = i; v < NV; v += n) {
        float4 l = reinterpret_cast<const float4*>(logits)[v];
        int4 g = reinterpret_cast<const int4*>(mb)[v];
        float4 o;
        o.x = __expf(l.x - gmax[g.x]) * ginv[g.x];
        o.y = __expf(l.y - gmax[g.y]) * ginv[g.y];
        o.z = __expf(l.z - gmax[g.z]) * ginv[g.z];
        o.w = __expf(l.w - gmax[g.w]) * ginv[g.w];
        reinterpret_cast<float4*>(out)[v] = o;
    }
}

extern "C" void kernel_launch(void* const* d_in, const int* in_sizes, int n_in,
                              void* d_out, int out_size, void* d_ws, size_t ws_size,
                              hipStream_t stream) {
    const float* emb = (const float*)d_in[0];
    const int* moves = (const int*)d_in[1];
    const int* batch = (const int*)d_in[2];
    const float* W1 = (const float*)d_in[3];
    const float* b1 = (const float*)d_in[4];
    const float* W2 = (const float*)d_in[5];
    const float* b2 = (const float*)d_in[6];
    float* out = (float*)d_out;

    auto al = [](size_t x) { return (x + 255) & ~(size_t)255; };
    char* ws = (char*)d_ws;
    size_t off = 0;
    ushort* W1t = (ushort*)(ws + off); off += al((size_t)512 * 256 * 2);
    ushort* P   = (ushort*)(ws + off); off += al((size_t)NNODES * 512 * 2);
    float* logits = (float*)(ws + off); off += al((size_t)NMOVES * 4);
    int* mb       = (int*)(ws + off);   off += al((size_t)NMOVES * 4);
    float* pmax   = (float*)(ws + off); off += al((size_t)PB * NGRAPHS * 4);
    float* psum   = (float*)(ws + off); off += al((size_t)PB * NGRAPHS * 4);
    float* gmax   = (float*)(ws + off); off += al((size_t)NGRAPHS * 4);
    float* ginv   = (float*)(ws + off); off += al((size_t)NGRAPHS * 4);

    k_convert_w1<<<512, 256, 0, stream>>>(W1, W1t);

    int tiles_m = (NNODES + BM - 1) / BM;   // 782
    k_gemm<<<tiles_m, 512, 0, stream>>>(emb, W1t, P, NNODES);

    k_moves<<<2048, 256, 0, stream>>>(moves, moves + NMOVES, batch, P, b1, W2, b2,
                                      logits, mb);
    k_part<<<PB, 256, 0, stream>>>(logits, mb, pmax, psum);
    k_combine<<<NGRAPHS, 64, 0, stream>>>(pmax, psum, gmax, ginv);
    k_norm<<<512, 256, 0, stream>>>(logits, mb, gmax, ginv, out);
}

// Round 12
// 185.050 us; speedup vs baseline: 1.9610x; 1.9610x over previous
//
#include <hip/hip_runtime.h>
#include <hip/hip_bf16.h>

#define NNODES 100000
#define HID 256
#define NMOVES 500000
#define NGRAPHS 512
#define BM 128
#define BN 32
#define PB 128   // partial-reduction blocks

typedef __attribute__((ext_vector_type(8))) short short8;
typedef __attribute__((ext_vector_type(4))) float f32x4;

#define AS_GLOBAL __attribute__((address_space(1)))
#define AS_LDS __attribute__((address_space(3)))

__device__ __forceinline__ unsigned f2bf(float f) {
    unsigned u = __builtin_bit_cast(unsigned, f);
    u += 0x7FFFu + ((u >> 16) & 1u);   // round-to-nearest-even
    return u >> 16;
}
__device__ __forceinline__ float bf2f(ushort h) {
    unsigned u = ((unsigned)h) << 16;
    return __builtin_bit_cast(float, u);
}
// order-preserving float<->uint encoding for max
__device__ __forceinline__ unsigned encf(float f) {
    unsigned b = __builtin_bit_cast(unsigned, f);
    return (b & 0x80000000u) ? ~b : (b ^ 0x80000000u);
}
__device__ __forceinline__ float decf(unsigned u) {
    unsigned b = (u & 0x80000000u) ? (u ^ 0x80000000u) : ~u;
    return __builtin_bit_cast(float, b);
}

// ---- build W1' transposed: W1t[n][k] ----
__global__ void k_convert_w1(const float* __restrict__ W1, ushort* __restrict__ W1t) {
    int t = blockIdx.x * blockDim.x + threadIdx.x; // 131072
    int n = t >> 8, k = t & 255;
    float v = (n < 256) ? W1[k * 256 + n] : W1[(k + 256) * 256 + (n - 256)];
    W1t[t] = (ushort)f2bf(v);
}

// ---- GEMM v4b: R11 structure, launch_bounds(512,4) so af[2][8] stays in
// registers (R11's (512,8) forced a <=64-reg cap -> af spilled to scratch,
// FETCH 52->522MB). A: direct global f32 loads, bf16 convert in-register.
// B: double-buffered BN=32 strips in 32KB LDS, gload_lds w=16, pre-swizzled
// source. Counted vmcnt: steady = stores(2)+stage(2) -> vmcnt(4).
__global__ __launch_bounds__(512, 4) void k_gemm(const float* __restrict__ emb,
                                                 const ushort* __restrict__ Bt,
                                                 ushort* __restrict__ P, int M) {
    __shared__ __align__(16) char lds[32768];   // 2 x 16KB B buffers
    int tid = threadIdx.x;
    int lane = tid & 63;
    int wave = tid >> 6;
    int tm = blockIdx.x * BM;
    int wm = wave >> 1;   // 0..3  (32-row group)
    int wn = wave & 1;    // 0..1  (16-col group within strip)
    int fr = lane & 15;
    int q = lane >> 4;    // 0..3
    int sw = fr & 7;

    // stage strip: 16KB = 512 thr x 2 x 16B; pre-swizzled source
#define STAGE(STRIP, BUFI)                                                          \
    {                                                                               \
        _Pragma("unroll")                                                           \
        for (int i = 0; i < 2; ++i) {                                               \
            int cid = i * 512 + tid;       /* 16B chunk 0..1023 */                  \
            int row = cid >> 5, c = cid & 31;                                       \
            const ushort* src = Bt + (size_t)((STRIP) * BN + row) * 256             \
                                   + ((c ^ (row & 7)) << 3);                        \
            __builtin_amdgcn_global_load_lds((const AS_GLOBAL void*)src,            \
                (AS_LDS void*)(lds + (BUFI) * 16384 + (i * 512 + wave * 64) * 16),  \
                16, 0, 0);                                                          \
        }                                                                           \
    }

    STAGE(0, 0);
    STAGE(1, 1);

    // ---- A fragments straight from global (f32 -> bf16 in-register) ----
    short8 af[2][8];
#pragma unroll
    for (int m = 0; m < 2; ++m) {
        int grow = tm + wm * 32 + m * 16 + fr;
        if (grow >= M) grow = M - 1;
        const float* base = emb + (size_t)grow * 256;
#pragma unroll
        for (int kt = 0; kt < 8; ++kt) {
            float4 v0 = *reinterpret_cast<const float4*>(base + (kt * 4 + q) * 8);
            float4 v1 = *reinterpret_cast<const float4*>(base + (kt * 4 + q) * 8 + 4);
            short8 f;
            f[0] = (short)f2bf(v0.x); f[1] = (short)f2bf(v0.y);
            f[2] = (short)f2bf(v0.z); f[3] = (short)f2bf(v0.w);
            f[4] = (short)f2bf(v1.x); f[5] = (short)f2bf(v1.y);
            f[6] = (short)f2bf(v1.z); f[7] = (short)f2bf(v1.w);
            af[m][kt] = f;
        }
    }

#pragma unroll 1
    for (int r = 0; r < 16; ++r) {
        // wait for stage(r); FIFO leaves stores(r-1)[2] + stage(r+1)[2]
        if (r < 15) asm volatile("s_waitcnt vmcnt(4)" ::: "memory");
        else        asm volatile("s_waitcnt vmcnt(2)" ::: "memory");
        asm volatile("s_barrier" ::: "memory");

        const char* bp = lds + (r & 1) * 16384;
        f32x4 acc0 = {0.f, 0.f, 0.f, 0.f};
        f32x4 acc1 = {0.f, 0.f, 0.f, 0.f};
#pragma unroll
        for (int kt = 0; kt < 8; ++kt) {
            short8 bf = *reinterpret_cast<const short8*>(
                bp + (wn * 16 + fr) * 512 + (((kt * 4 + q) ^ sw) << 4));
            acc0 = __builtin_amdgcn_mfma_f32_16x16x32_bf16(bf, af[0][kt], acc0, 0, 0, 0);
            acc1 = __builtin_amdgcn_mfma_f32_16x16x32_bf16(bf, af[1][kt], acc1, 0, 0, 0);
        }
        // packed epilogue: lane fr = P-row, regs = 4 consecutive P-cols
        int pcol = r * BN + wn * 16 + q * 4;
        int prow0 = tm + wm * 32 + fr;
        if (prow0 < M) {
            uint2 pk;
            pk.x = f2bf(acc0[0]) | (f2bf(acc0[1]) << 16);
            pk.y = f2bf(acc0[2]) | (f2bf(acc0[3]) << 16);
            *reinterpret_cast<uint2*>(P + (size_t)prow0 * 512 + pcol) = pk;
        }
        int prow1 = prow0 + 16;
        if (prow1 < M) {
            uint2 pk;
            pk.x = f2bf(acc1[0]) | (f2bf(acc1[1]) << 16);
            pk.y = f2bf(acc1[2]) | (f2bf(acc1[3]) << 16);
            *reinterpret_cast<uint2*>(P + (size_t)prow1 * 512 + pcol) = pk;
        }

        asm volatile("s_barrier" ::: "memory");   // all waves done reading buf
        if (r < 14) STAGE(r + 2, (r & 1));
    }
#undef STAGE
}

// ---- per-move MLP tail: 16 lanes/move, 4 moves/wave, unroll x2. NO atomics ----
__device__ __forceinline__ float dot8(uint4 a, uint4 b, const float* b1v, const float* w2v, int o) {
    unsigned aw[4] = {a.x, a.y, a.z, a.w};
    unsigned bw[4] = {b.x, b.y, b.z, b.w};
    float r = 0.f;
#pragma unroll
    for (int i = 0; i < 4; ++i) {
        float a0 = bf2f((ushort)(aw[i] & 0xffffu));
        float a1 = bf2f((ushort)(aw[i] >> 16));
        float c0 = bf2f((ushort)(bw[i] & 0xffffu));
        float c1 = bf2f((ushort)(bw[i] >> 16));
        float h0 = fmaxf(a0 + c0 + b1v[o + 2 * i], 0.f);
        float h1 = fmaxf(a1 + c1 + b1v[o + 2 * i + 1], 0.f);
        r += h0 * w2v[o + 2 * i] + h1 * w2v[o + 2 * i + 1];
    }
    return r;
}

__global__ __launch_bounds__(256) void k_moves(const int* __restrict__ srcs,
                                               const int* __restrict__ tgts,
                                               const int* __restrict__ batch,
                                               const ushort* __restrict__ P,
                                               const float* __restrict__ b1,
                                               const float* __restrict__ W2,
                                               const float* __restrict__ b2,
                                               float* __restrict__ logits,
                                               int* __restrict__ mb) {
    int tid = threadIdx.x;
    int lane = tid & 63;
    int sub = lane >> 4;
    int ch = lane & 15;

    float b1v[16], w2v[16];
    const float4* b1p = reinterpret_cast<const float4*>(b1);
    const float4* w2p = reinterpret_cast<const float4*>(W2);
#pragma unroll
    for (int q = 0; q < 4; ++q) {
        float4 bv = b1p[ch * 4 + q];
        float4 wv = w2p[ch * 4 + q];
        b1v[q * 4 + 0] = bv.x; b1v[q * 4 + 1] = bv.y; b1v[q * 4 + 2] = bv.z; b1v[q * 4 + 3] = bv.w;
        w2v[q * 4 + 0] = wv.x; w2v[q * 4 + 1] = wv.y; w2v[q * 4 + 2] = wv.z; w2v[q * 4 + 3] = wv.w;
    }
    float b2s = b2[0];

    int wid = (blockIdx.x * 256 + tid) >> 6;
    int nw = (gridDim.x * 256) >> 6;

    for (int base = wid * 8; base < NMOVES; base += nw * 8) {
        int m0 = base + sub;
        int m1 = base + 4 + sub;
        int s0 = srcs[m0], t0 = tgts[m0];
        int s1 = srcs[m1], t1 = tgts[m1];
        const uint4* pa0 = reinterpret_cast<const uint4*>(P + (size_t)s0 * 512 + ch * 16);
        const uint4* pb0 = reinterpret_cast<const uint4*>(P + (size_t)t0 * 512 + 256 + ch * 16);
        const uint4* pa1 = reinterpret_cast<const uint4*>(P + (size_t)s1 * 512 + ch * 16);
        const uint4* pb1 = reinterpret_cast<const uint4*>(P + (size_t)t1 * 512 + 256 + ch * 16);
        uint4 a00 = pa0[0], a01 = pa0[1];
        uint4 c00 = pb0[0], c01 = pb0[1];
        uint4 a10 = pa1[0], a11 = pa1[1];
        uint4 c10 = pb1[0], c11 = pb1[1];
        int g0 = batch[s0];
        int g1 = batch[s1];

        float p0 = dot8(a00, c00, b1v, w2v, 0) + dot8(a01, c01, b1v, w2v, 8);
        float p1 = dot8(a10, c10, b1v, w2v, 0) + dot8(a11, c11, b1v, w2v, 8);
#pragma unroll
        for (int off = 1; off < 16; off <<= 1) {
            p0 += __shfl_xor(p0, off);
            p1 += __shfl_xor(p1, off);
        }
        if (ch == 0) {
            logits[m0] = p0 + b2s; mb[m0] = g0;
            logits[m1] = p1 + b2s; mb[m1] = g1;
        }
    }
}

// ---- per-block segment partials (vectorized 4 moves/thread) ----
__global__ __launch_bounds__(256) void k_part(const float* __restrict__ logits,
                                              const int* __restrict__ mb,
                                              float* __restrict__ pmax,
                                              float* __restrict__ psum) {
    __shared__ unsigned lmax[NGRAPHS];
    __shared__ float lsum[NGRAPHS];
    int tid = threadIdx.x;
    lmax[tid] = 0u; lmax[tid + 256] = 0u;
    lsum[tid] = 0.f; lsum[tid + 256] = 0.f;
    __syncthreads();

    const int NV = NMOVES / 4;
    int stride = PB * 256;
    for (int v = blockIdx.x * 256 + tid; v < NV; v += stride) {
        float4 l = reinterpret_cast<const float4*>(logits)[v];
        int4 g = reinterpret_cast<const int4*>(mb)[v];
        atomicMax(&lmax[g.x], encf(l.x));
        atomicMax(&lmax[g.y], encf(l.y));
        atomicMax(&lmax[g.z], encf(l.z));
        atomicMax(&lmax[g.w], encf(l.w));
    }
    __syncthreads();
    for (int v = blockIdx.x * 256 + tid; v < NV; v += stride) {
        float4 l = reinterpret_cast<const float4*>(logits)[v];
        int4 g = reinterpret_cast<const int4*>(mb)[v];
        atomicAdd(&lsum[g.x], __expf(l.x - decf(lmax[g.x])));
        atomicAdd(&lsum[g.y], __expf(l.y - decf(lmax[g.y])));
        atomicAdd(&lsum[g.z], __expf(l.z - decf(lmax[g.z])));
        atomicAdd(&lsum[g.w], __expf(l.w - decf(lmax[g.w])));
    }
    __syncthreads();

#pragma unroll
    for (int i = 0; i < 2; ++i) {
        int s = tid + i * 256;
        unsigned e = lmax[s];
        pmax[blockIdx.x * NGRAPHS + s] = (e == 0u) ? -INFINITY : decf(e);
        psum[blockIdx.x * NGRAPHS + s] = lsum[s];
    }
}

// ---- fold PB partials per segment: one block per segment, wave-parallel ----
__global__ __launch_bounds__(64) void k_combine(const float* __restrict__ pmax,
                                                const float* __restrict__ psum,
                                                float* __restrict__ gmax,
                                                float* __restrict__ ginv) {
    int s = blockIdx.x;      // segment 0..511
    int lane = threadIdx.x;  // 0..63
    float pm0 = pmax[lane * NGRAPHS + s];
    float pm1 = pmax[(lane + 64) * NGRAPHS + s];
    float ps0 = psum[lane * NGRAPHS + s];
    float ps1 = psum[(lane + 64) * NGRAPHS + s];
    float M = fmaxf(pm0, pm1);
#pragma unroll
    for (int off = 32; off; off >>= 1) M = fmaxf(M, __shfl_xor(M, off));
    float S = (ps0 > 0.f ? ps0 * __expf(pm0 - M) : 0.f)
            + (ps1 > 0.f ? ps1 * __expf(pm1 - M) : 0.f);
#pragma unroll
    for (int off = 32; off; off >>= 1) S += __shfl_xor(S, off);
    if (lane == 0) {
        gmax[s] = M;
        ginv[s] = 1.f / (S + 1e-16f);
    }
}

// ---- normalize (vectorized 4 moves/thread) ----
__global__ void k_norm(const float* __restrict__ logits, const int* __restrict__ mb,
                       const float* __restrict__ gmax, const float* __restrict__ ginv,
                       float* __restrict__ out) {
    const int NV = NMOVES / 4;
    int i = blockIdx.x * blockDim.x + threadIdx.x;
    int n = gridDim.x * blockDim.x;
    for (int v = i; v < NV; v += n) {
        float4 l = reinterpret_cast<const float4*>(logits)[v];
        int4 g = reinterpret_cast<const int4*>(mb)[v];
        float4 o;
        o.x = __expf(l.x - gmax[g.x]) * ginv[g.x];
        o.y = __expf(l.y - gmax[g.y]) * ginv[g.y];
        o.z = __expf(l.z - gmax[g.z]) * ginv[g.z];
        o.w = __expf(l.w - gmax[g.w]) * ginv[g.w];
        reinterpret_cast<float4*>(out)[v] = o;
    }
}

extern "C" void kernel_launch(void* const* d_in, const int* in_sizes, int n_in,
                              void* d_out, int out_size, void* d_ws, size_t ws_size,
                              hipStream_t stream) {
    const float* emb = (const float*)d_in[0];
    const int* moves = (const int*)d_in[1];
    const int* batch = (const int*)d_in[2];
    const float* W1 = (const float*)d_in[3];
    const float* b1 = (const float*)d_in[4];
    const float* W2 = (const float*)d_in[5];
    const float* b2 = (const float*)d_in[6];
    float* out = (float*)d_out;

    auto al = [](size_t x) { return (x + 255) & ~(size_t)255; };
    char* ws = (char*)d_ws;
    size_t off = 0;
    ushort* W1t = (ushort*)(ws + off); off += al((size_t)512 * 256 * 2);
    ushort* P   = (ushort*)(ws + off); off += al((size_t)NNODES * 512 * 2);
    float* logits = (float*)(ws + off); off += al((size_t)NMOVES * 4);
    int* mb       = (int*)(ws + off);   off += al((size_t)NMOVES * 4);
    float* pmax   = (float*)(ws + off); off += al((size_t)PB * NGRAPHS * 4);
    float* psum   = (float*)(ws + off); off += al((size_t)PB * NGRAPHS * 4);
    float* gmax   = (float*)(ws + off); off += al((size_t)NGRAPHS * 4);
    float* ginv   = (float*)(ws + off); off += al((size_t)NGRAPHS * 4);

    k_convert_w1<<<512, 256, 0, stream>>>(W1, W1t);

    int tiles_m = (NNODES + BM - 1) / BM;   // 782
    k_gemm<<<tiles_m, 512, 0, stream>>>(emb, W1t, P, NNODES);

    k_moves<<<2048, 256, 0, stream>>>(moves, moves + NMOVES, batch, P, b1, W2, b2,
                                      logits, mb);
    k_part<<<PB, 256, 0, stream>>>(logits, mb, pmax, psum);
    k_combine<<<NGRAPHS, 64, 0, stream>>>(pmax, psum, gmax, ginv);
    k_norm<<<512, 256, 0, stream>>>(logits, mb, gmax, ginv, out);
}

// Round 13
// 159.923 us; speedup vs baseline: 2.2691x; 1.1571x over previous
//
#include <hip/hip_runtime.h>
#include <hip/hip_bf16.h>

#define NNODES 100000
#define HID 256
#define NMOVES 500000
#define NGRAPHS 512
#define BM 128
#define BN 32
#define PB 128   // partial-reduction blocks

typedef __attribute__((ext_vector_type(8))) short short8;
typedef __attribute__((ext_vector_type(4))) float f32x4;

#define AS_GLOBAL __attribute__((address_space(1)))
#define AS_LDS __attribute__((address_space(3)))

__device__ __forceinline__ unsigned f2bf(float f) {
    unsigned u = __builtin_bit_cast(unsigned, f);
    u += 0x7FFFu + ((u >> 16) & 1u);   // round-to-nearest-even
    return u >> 16;
}
__device__ __forceinline__ float bf2f(ushort h) {
    unsigned u = ((unsigned)h) << 16;
    return __builtin_bit_cast(float, u);
}
// order-preserving float<->uint encoding for max
__device__ __forceinline__ unsigned encf(float f) {
    unsigned b = __builtin_bit_cast(unsigned, f);
    return (b & 0x80000000u) ? ~b : (b ^ 0x80000000u);
}
__device__ __forceinline__ float decf(unsigned u) {
    unsigned b = (u & 0x80000000u) ? (u ^ 0x80000000u) : ~u;
    return __builtin_bit_cast(float, b);
}

// ---- build W1' transposed: W1t[n][k] ----
__global__ void k_convert_w1(const float* __restrict__ W1, ushort* __restrict__ W1t) {
    int t = blockIdx.x * blockDim.x + threadIdx.x; // 131072
    int n = t >> 8, k = t & 255;
    float v = (n < 256) ? W1[k * 256 + n] : W1[(k + 256) * 256 + (n - 256)];
    W1t[t] = (ushort)f2bf(v);
}

// ---- GEMM (R9 structure + packed epilogue): P = emb @ [W1_top | W1_bot] ----
// Phase 1: A panel 128x256 staged cooperatively (coalesced 1KB-row reads,
// f32->bf16 in-register, XOR-swizzled ds_write). Phase 2: af extract to regs.
// Phase 3: LDS overlaid by double-buffered BN=32 B strips (gload_lds w=16,
// pre-swizzled source), counted vmcnt (never 0 mid-loop). Swapped-operand
// MFMA (R7/R12-verified): acc regs = 4 consecutive P-cols -> 2 uint2 stores.
__global__ __launch_bounds__(512, 4) void k_gemm(const float* __restrict__ emb,
                                                 const ushort* __restrict__ Bt,
                                                 ushort* __restrict__ P, int M) {
    __shared__ __align__(16) char lds[65536];
    int tid = threadIdx.x;
    int lane = tid & 63;
    int wave = tid >> 6;
    int tm = blockIdx.x * BM;
    int wm = wave >> 1;   // 0..3  (32-row group)
    int wn = wave & 1;    // 0..1  (16-col group within strip)
    int fr = lane & 15;
    int q = lane >> 4;    // 0..3
    int sw = fr & 7;

    // ---- Phase 1: stage A 128x256 (f32->bf16, swizzled ds_write) ----
#pragma unroll
    for (int i = 0; i < 8; ++i) {
        int cid = i * 512 + tid;         // 16B-bf16 chunk id, 0..4095
        int row = cid >> 5;              // 0..127
        int j = cid & 31;
        int grow = tm + row; if (grow >= M) grow = M - 1;
        const float4* sp = reinterpret_cast<const float4*>(emb + (size_t)grow * 256 + (j << 3));
        float4 v0 = sp[0], v1 = sp[1];
        uint4 o;
        o.x = f2bf(v0.x) | (f2bf(v0.y) << 16);
        o.y = f2bf(v0.z) | (f2bf(v0.w) << 16);
        o.z = f2bf(v1.x) | (f2bf(v1.y) << 16);
        o.w = f2bf(v1.z) | (f2bf(v1.w) << 16);
        *reinterpret_cast<uint4*>(lds + row * 512 + ((j ^ (row & 7)) << 4)) = o;
    }
    __syncthreads();

    // ---- Phase 2: A fragments -> registers (16 x short8) ----
    short8 af[2][8];
#pragma unroll
    for (int m = 0; m < 2; ++m) {
        int row = wm * 32 + m * 16 + fr;
#pragma unroll
        for (int kt = 0; kt < 8; ++kt)
            af[m][kt] = *reinterpret_cast<const short8*>(
                lds + row * 512 + (((kt * 4 + q) ^ sw) << 4));
    }
    __syncthreads();   // all waves extracted; lds region now free for B

    // ---- Phase 3: 16 B strips (BN=32), double-buffered, counted vmcnt ----
#define STAGE(STRIP, BUFI)                                                          \
    {                                                                               \
        _Pragma("unroll")                                                           \
        for (int i = 0; i < 2; ++i) {                                               \
            int cid = i * 512 + tid;       /* 16B chunk 0..1023 */                  \
            int row = cid >> 5, c = cid & 31;                                       \
            const ushort* src = Bt + (size_t)((STRIP) * BN + row) * 256             \
                                   + ((c ^ (row & 7)) << 3);                        \
            __builtin_amdgcn_global_load_lds((const AS_GLOBAL void*)src,            \
                (AS_LDS void*)(lds + (BUFI) * 16384 + (i * 512 + wave * 64) * 16),  \
                16, 0, 0);                                                          \
        }                                                                           \
    }

    STAGE(0, 0);
    STAGE(1, 1);

#pragma unroll 1
    for (int r = 0; r < 16; ++r) {
        // FIFO at iter r: [stores(r-2), stage(r), stores(r-1), stage(r+1)]
        // want stage(r) done: r=0 -> 2 outstanding after; steady -> 4; last -> 2
        if (r == 0)      asm volatile("s_waitcnt vmcnt(2)" ::: "memory");
        else if (r < 15) asm volatile("s_waitcnt vmcnt(4)" ::: "memory");
        else             asm volatile("s_waitcnt vmcnt(2)" ::: "memory");
        asm volatile("s_barrier" ::: "memory");

        const char* bp = lds + (r & 1) * 16384;
        f32x4 acc0 = {0.f, 0.f, 0.f, 0.f};
        f32x4 acc1 = {0.f, 0.f, 0.f, 0.f};
#pragma unroll
        for (int kt = 0; kt < 8; ++kt) {
            short8 bf = *reinterpret_cast<const short8*>(
                bp + (wn * 16 + fr) * 512 + (((kt * 4 + q) ^ sw) << 4));
            acc0 = __builtin_amdgcn_mfma_f32_16x16x32_bf16(bf, af[0][kt], acc0, 0, 0, 0);
            acc1 = __builtin_amdgcn_mfma_f32_16x16x32_bf16(bf, af[1][kt], acc1, 0, 0, 0);
        }
        // packed epilogue: lane fr = P-row, regs = 4 consecutive P-cols
        int pcol = r * BN + wn * 16 + q * 4;
        int prow0 = tm + wm * 32 + fr;
        if (prow0 < M) {
            uint2 pk;
            pk.x = f2bf(acc0[0]) | (f2bf(acc0[1]) << 16);
            pk.y = f2bf(acc0[2]) | (f2bf(acc0[3]) << 16);
            *reinterpret_cast<uint2*>(P + (size_t)prow0 * 512 + pcol) = pk;
        }
        int prow1 = prow0 + 16;
        if (prow1 < M) {
            uint2 pk;
            pk.x = f2bf(acc1[0]) | (f2bf(acc1[1]) << 16);
            pk.y = f2bf(acc1[2]) | (f2bf(acc1[3]) << 16);
            *reinterpret_cast<uint2*>(P + (size_t)prow1 * 512 + pcol) = pk;
        }

        asm volatile("s_barrier" ::: "memory");   // all waves done reading buf
        if (r < 14) STAGE(r + 2, (r & 1));
    }
#undef STAGE
}

// ---- per-move MLP tail: 16 lanes/move, 4 moves/wave, unroll x2. NO atomics ----
__device__ __forceinline__ float dot8(uint4 a, uint4 b, const float* b1v, const float* w2v, int o) {
    unsigned aw[4] = {a.x, a.y, a.z, a.w};
    unsigned bw[4] = {b.x, b.y, b.z, b.w};
    float r = 0.f;
#pragma unroll
    for (int i = 0; i < 4; ++i) {
        float a0 = bf2f((ushort)(aw[i] & 0xffffu));
        float a1 = bf2f((ushort)(aw[i] >> 16));
        float c0 = bf2f((ushort)(bw[i] & 0xffffu));
        float c1 = bf2f((ushort)(bw[i] >> 16));
        float h0 = fmaxf(a0 + c0 + b1v[o + 2 * i], 0.f);
        float h1 = fmaxf(a1 + c1 + b1v[o + 2 * i + 1], 0.f);
        r += h0 * w2v[o + 2 * i] + h1 * w2v[o + 2 * i + 1];
    }
    return r;
}

__global__ __launch_bounds__(256) void k_moves(const int* __restrict__ srcs,
                                               const int* __restrict__ tgts,
                                               const int* __restrict__ batch,
                                               const ushort* __restrict__ P,
                                               const float* __restrict__ b1,
                                               const float* __restrict__ W2,
                                               const float* __restrict__ b2,
                                               float* __restrict__ logits,
                                               int* __restrict__ mb) {
    int tid = threadIdx.x;
    int lane = tid & 63;
    int sub = lane >> 4;
    int ch = lane & 15;

    float b1v[16], w2v[16];
    const float4* b1p = reinterpret_cast<const float4*>(b1);
    const float4* w2p = reinterpret_cast<const float4*>(W2);
#pragma unroll
    for (int q = 0; q < 4; ++q) {
        float4 bv = b1p[ch * 4 + q];
        float4 wv = w2p[ch * 4 + q];
        b1v[q * 4 + 0] = bv.x; b1v[q * 4 + 1] = bv.y; b1v[q * 4 + 2] = bv.z; b1v[q * 4 + 3] = bv.w;
        w2v[q * 4 + 0] = wv.x; w2v[q * 4 + 1] = wv.y; w2v[q * 4 + 2] = wv.z; w2v[q * 4 + 3] = wv.w;
    }
    float b2s = b2[0];

    int wid = (blockIdx.x * 256 + tid) >> 6;
    int nw = (gridDim.x * 256) >> 6;

    for (int base = wid * 8; base < NMOVES; base += nw * 8) {
        int m0 = base + sub;
        int m1 = base + 4 + sub;
        int s0 = srcs[m0], t0 = tgts[m0];
        int s1 = srcs[m1], t1 = tgts[m1];
        const uint4* pa0 = reinterpret_cast<const uint4*>(P + (size_t)s0 * 512 + ch * 16);
        const uint4* pb0 = reinterpret_cast<const uint4*>(P + (size_t)t0 * 512 + 256 + ch * 16);
        const uint4* pa1 = reinterpret_cast<const uint4*>(P + (size_t)s1 * 512 + ch * 16);
        const uint4* pb1 = reinterpret_cast<const uint4*>(P + (size_t)t1 * 512 + 256 + ch * 16);
        uint4 a00 = pa0[0], a01 = pa0[1];
        uint4 c00 = pb0[0], c01 = pb0[1];
        uint4 a10 = pa1[0], a11 = pa1[1];
        uint4 c10 = pb1[0], c11 = pb1[1];
        int g0 = batch[s0];
        int g1 = batch[s1];

        float p0 = dot8(a00, c00, b1v, w2v, 0) + dot8(a01, c01, b1v, w2v, 8);
        float p1 = dot8(a10, c10, b1v, w2v, 0) + dot8(a11, c11, b1v, w2v, 8);
#pragma unroll
        for (int off = 1; off < 16; off <<= 1) {
            p0 += __shfl_xor(p0, off);
            p1 += __shfl_xor(p1, off);
        }
        if (ch == 0) {
            logits[m0] = p0 + b2s; mb[m0] = g0;
            logits[m1] = p1 + b2s; mb[m1] = g1;
        }
    }
}

// ---- per-block segment partials (vectorized 4 moves/thread) ----
__global__ __launch_bounds__(256) void k_part(const float* __restrict__ logits,
                                              const int* __restrict__ mb,
                                              float* __restrict__ pmax,
                                              float* __restrict__ psum) {
    __shared__ unsigned lmax[NGRAPHS];
    __shared__ float lsum[NGRAPHS];
    int tid = threadIdx.x;
    lmax[tid] = 0u; lmax[tid + 256] = 0u;
    lsum[tid] = 0.f; lsum[tid + 256] = 0.f;
    __syncthreads();

    const int NV = NMOVES / 4;
    int stride = PB * 256;
    for (int v = blockIdx.x * 256 + tid; v < NV; v += stride) {
        float4 l = reinterpret_cast<const float4*>(logits)[v];
        int4 g = reinterpret_cast<const int4*>(mb)[v];
        atomicMax(&lmax[g.x], encf(l.x));
        atomicMax(&lmax[g.y], encf(l.y));
        atomicMax(&lmax[g.z], encf(l.z));
        atomicMax(&lmax[g.w], encf(l.w));
    }
    __syncthreads();
    for (int v = blockIdx.x * 256 + tid; v < NV; v += stride) {
        float4 l = reinterpret_cast<const float4*>(logits)[v];
        int4 g = reinterpret_cast<const int4*>(mb)[v];
        atomicAdd(&lsum[g.x], __expf(l.x - decf(lmax[g.x])));
        atomicAdd(&lsum[g.y], __expf(l.y - decf(lmax[g.y])));
        atomicAdd(&lsum[g.z], __expf(l.z - decf(lmax[g.z])));
        atomicAdd(&lsum[g.w], __expf(l.w - decf(lmax[g.w])));
    }
    __syncthreads();

#pragma unroll
    for (int i = 0; i < 2; ++i) {
        int s = tid + i * 256;
        unsigned e = lmax[s];
        pmax[blockIdx.x * NGRAPHS + s] = (e == 0u) ? -INFINITY : decf(e);
        psum[blockIdx.x * NGRAPHS + s] = lsum[s];
    }
}

// ---- fold PB partials per segment: one block per segment, wave-parallel ----
__global__ __launch_bounds__(64) void k_combine(const float* __restrict__ pmax,
                                                const float* __restrict__ psum,
                                                float* __restrict__ gmax,
                                                float* __restrict__ ginv) {
    int s = blockIdx.x;      // segment 0..511
    int lane = threadIdx.x;  // 0..63
    float pm0 = pmax[lane * NGRAPHS + s];
    float pm1 = pmax[(lane + 64) * NGRAPHS + s];
    float ps0 = psum[lane * NGRAPHS + s];
    float ps1 = psum[(lane + 64) * NGRAPHS + s];
    float M = fmaxf(pm0, pm1);
#pragma unroll
    for (int off = 32; off; off >>= 1) M = fmaxf(M, __shfl_xor(M, off));
    float S = (ps0 > 0.f ? ps0 * __expf(pm0 - M) : 0.f)
            + (ps1 > 0.f ? ps1 * __expf(pm1 - M) : 0.f);
#pragma unroll
    for (int off = 32; off; off >>= 1) S += __shfl_xor(S, off);
    if (lane == 0) {
        gmax[s] = M;
        ginv[s] = 1.f / (S + 1e-16f);
    }
}

// ---- normalize (vectorized 4 moves/thread) ----
__global__ void k_norm(const float* __restrict__ logits, const int* __restrict__ mb,
                       const float* __restrict__ gmax, const float* __restrict__ ginv,
                       float* __restrict__ out) {
    const int NV = NMOVES / 4;
    int i = blockIdx.x * blockDim.x + threadIdx.x;
    int n = gridDim.x * blockDim.x;
    for (int v = i; v < NV; v += n) {
        float4 l = reinterpret_cast<const float4*>(logits)[v];
        int4 g = reinterpret_cast<const int4*>(mb)[v];
        float4 o;
        o.x = __expf(l.x - gmax[g.x]) * ginv[g.x];
        o.y = __expf(l.y - gmax[g.y]) * ginv[g.y];
        o.z = __expf(l.z - gmax[g.z]) * ginv[g.z];
        o.w = __expf(l.w - gmax[g.w]) * ginv[g.w];
        reinterpret_cast<float4*>(out)[v] = o;
    }
}

extern "C" void kernel_launch(void* const* d_in, const int* in_sizes, int n_in,
                              void* d_out, int out_size, void* d_ws, size_t ws_size,
                              hipStream_t stream) {
    const float* emb = (const float*)d_in[0];
    const int* moves = (const int*)d_in[1];
    const int* batch = (const int*)d_in[2];
    const float* W1 = (const float*)d_in[3];
    const float* b1 = (const float*)d_in[4];
    const float* W2 = (const float*)d_in[5];
    const float* b2 = (const float*)d_in[6];
    float* out = (float*)d_out;

    auto al = [](size_t x) { return (x + 255) & ~(size_t)255; };
    char* ws = (char*)d_ws;
    size_t off = 0;
    ushort* W1t = (ushort*)(ws + off); off += al((size_t)512 * 256 * 2);
    ushort* P   = (ushort*)(ws + off); off += al((size_t)NNODES * 512 * 2);
    float* logits = (float*)(ws + off); off += al((size_t)NMOVES * 4);
    int* mb       = (int*)(ws + off);   off += al((size_t)NMOVES * 4);
    float* pmax   = (float*)(ws + off); off += al((size_t)PB * NGRAPHS * 4);
    float* psum   = (float*)(ws + off); off += al((size_t)PB * NGRAPHS * 4);
    float* gmax   = (float*)(ws + off); off += al((size_t)NGRAPHS * 4);
    float* ginv   = (float*)(ws + off); off += al((size_t)NGRAPHS * 4);

    k_convert_w1<<<512, 256, 0, stream>>>(W1, W1t);

    int tiles_m = (NNODES + BM - 1) / BM;   // 782
    k_gemm<<<tiles_m, 512, 0, stream>>>(emb, W1t, P, NNODES);

    k_moves<<<2048, 256, 0, stream>>>(moves, moves + NMOVES, batch, P, b1, W2, b2,
                                      logits, mb);
    k_part<<<PB, 256, 0, stream>>>(logits, mb, pmax, psum);
    k_combine<<<NGRAPHS, 64, 0, stream>>>(pmax, psum, gmax, ginv);
    k_norm<<<512, 256, 0, stream>>>(logits, mb, gmax, ginv, out);
}

// Round 14
// 153.410 us; speedup vs baseline: 2.3654x; 1.0425x over previous
//
#include <hip/hip_runtime.h>
#include <hip/hip_bf16.h>

#define NNODES 100000
#define HID 256
#define NMOVES 500000
#define NGRAPHS 512
#define BM 128
#define BN 32
#define PBM 2048   // partial blocks = k_moves grid

typedef __attribute__((ext_vector_type(8))) short short8;
typedef __attribute__((ext_vector_type(4))) float f32x4;

#define AS_GLOBAL __attribute__((address_space(1)))
#define AS_LDS __attribute__((address_space(3)))

__device__ __forceinline__ unsigned f2bf(float f) {
    unsigned u = __builtin_bit_cast(unsigned, f);
    u += 0x7FFFu + ((u >> 16) & 1u);   // round-to-nearest-even
    return u >> 16;
}
__device__ __forceinline__ float bf2f(ushort h) {
    unsigned u = ((unsigned)h) << 16;
    return __builtin_bit_cast(float, u);
}
// order-preserving float<->uint encoding for max
__device__ __forceinline__ unsigned encf(float f) {
    unsigned b = __builtin_bit_cast(unsigned, f);
    return (b & 0x80000000u) ? ~b : (b ^ 0x80000000u);
}
__device__ __forceinline__ float decf(unsigned u) {
    unsigned b = (u & 0x80000000u) ? (u ^ 0x80000000u) : ~u;
    return __builtin_bit_cast(float, b);
}

// ---- build W1' transposed: W1t[n][k] ----
__global__ void k_convert_w1(const float* __restrict__ W1, ushort* __restrict__ W1t) {
    int t = blockIdx.x * blockDim.x + threadIdx.x; // 131072
    int n = t >> 8, k = t & 255;
    float v = (n < 256) ? W1[k * 256 + n] : W1[(k + 256) * 256 + (n - 256)];
    W1t[t] = (ushort)f2bf(v);
}

// ---- GEMM: verbatim R9 (82us proven; every restructure R10-R13 regressed) ----
__global__ __launch_bounds__(512, 4) void k_gemm(const float* __restrict__ emb,
                                                 const ushort* __restrict__ Bt,
                                                 ushort* __restrict__ P, int M) {
    __shared__ __align__(16) char lds[65536];
    int tid = threadIdx.x;
    int lane = tid & 63;
    int wave = tid >> 6;
    int tm = blockIdx.x * BM;
    int wm = wave >> 1;   // 0..3  (32-row group)
    int wn = wave & 1;    // 0..1  (16-col group within strip)
    int fr = lane & 15;
    int q = lane >> 4;    // 0..3
    int sw = fr & 7;

    // ---- Phase 1: stage A 128x256 (f32->bf16, swizzled ds_write) ----
#pragma unroll
    for (int i = 0; i < 8; ++i) {
        int cid = i * 512 + tid;         // 16B-bf16 chunk id, 0..4095
        int row = cid >> 5;              // 0..127
        int j = cid & 31;
        int grow = tm + row; if (grow >= M) grow = M - 1;
        const float4* sp = reinterpret_cast<const float4*>(emb + (size_t)grow * 256 + (j << 3));
        float4 v0 = sp[0], v1 = sp[1];
        uint4 o;
        o.x = f2bf(v0.x) | (f2bf(v0.y) << 16);
        o.y = f2bf(v0.z) | (f2bf(v0.w) << 16);
        o.z = f2bf(v1.x) | (f2bf(v1.y) << 16);
        o.w = f2bf(v1.z) | (f2bf(v1.w) << 16);
        *reinterpret_cast<uint4*>(lds + row * 512 + ((j ^ (row & 7)) << 4)) = o;
    }
    __syncthreads();

    // ---- Phase 2: A fragments -> registers (16 x short8) ----
    short8 af[2][8];
#pragma unroll
    for (int m = 0; m < 2; ++m) {
        int row = wm * 32 + m * 16 + fr;
#pragma unroll
        for (int kt = 0; kt < 8; ++kt)
            af[m][kt] = *reinterpret_cast<const short8*>(
                lds + row * 512 + (((kt * 4 + q) ^ sw) << 4));
    }
    __syncthreads();   // all waves extracted; lds region now free for B

    // ---- Phase 3: 16 B strips (BN=32), double-buffered, counted vmcnt ----
#define STAGE(STRIP, BUFI)                                                          \
    {                                                                               \
        _Pragma("unroll")                                                           \
        for (int i = 0; i < 2; ++i) {                                               \
            int cid = i * 512 + tid;       /* 16B chunk 0..1023 */                  \
            int row = cid >> 5, c = cid & 31;                                       \
            const ushort* src = Bt + (size_t)((STRIP) * BN + row) * 256             \
                                   + ((c ^ (row & 7)) << 3);                        \
            __builtin_amdgcn_global_load_lds((const AS_GLOBAL void*)src,            \
                (AS_LDS void*)(lds + (BUFI) * 16384 + (i * 512 + wave * 64) * 16),  \
                16, 0, 0);                                                          \
        }                                                                           \
    }

    STAGE(0, 0);
    STAGE(1, 1);

#pragma unroll 1
    for (int r = 0; r < 16; ++r) {
        if (r == 0)      asm volatile("s_waitcnt vmcnt(2)" ::: "memory");
        else if (r < 15) asm volatile("s_waitcnt vmcnt(10)" ::: "memory");
        else             asm volatile("s_waitcnt vmcnt(8)" ::: "memory");
        asm volatile("s_barrier" ::: "memory");

        const char* bp = lds + (r & 1) * 16384;
        f32x4 acc0 = {0.f, 0.f, 0.f, 0.f};
        f32x4 acc1 = {0.f, 0.f, 0.f, 0.f};
#pragma unroll
        for (int kt = 0; kt < 8; ++kt) {
            short8 bf = *reinterpret_cast<const short8*>(
                bp + (wn * 16 + fr) * 512 + (((kt * 4 + q) ^ sw) << 4));
            acc0 = __builtin_amdgcn_mfma_f32_16x16x32_bf16(af[0][kt], bf, acc0, 0, 0, 0);
            acc1 = __builtin_amdgcn_mfma_f32_16x16x32_bf16(af[1][kt], bf, acc1, 0, 0, 0);
        }
        // epilogue: lane = P-col (fr), rows q*4+j; 8 ushort stores, 32B sectors
        int pcol = r * BN + wn * 16 + fr;
#pragma unroll
        for (int j = 0; j < 4; ++j) {
            int prow0 = tm + wm * 32 + q * 4 + j;
            if (prow0 < M) P[(size_t)prow0 * 512 + pcol] = (ushort)f2bf(acc0[j]);
            int prow1 = prow0 + 16;
            if (prow1 < M) P[(size_t)prow1 * 512 + pcol] = (ushort)f2bf(acc1[j]);
        }

        asm volatile("s_barrier" ::: "memory");
        if (r < 14) STAGE(r + 2, (r & 1));
    }
#undef STAGE
}

// ---- per-move MLP tail + FUSED segment partials (k_part folded in) ----
__device__ __forceinline__ float dot8(uint4 a, uint4 b, const float* b1v, const float* w2v, int o) {
    unsigned aw[4] = {a.x, a.y, a.z, a.w};
    unsigned bw[4] = {b.x, b.y, b.z, b.w};
    float r = 0.f;
#pragma unroll
    for (int i = 0; i < 4; ++i) {
        float a0 = bf2f((ushort)(aw[i] & 0xffffu));
        float a1 = bf2f((ushort)(aw[i] >> 16));
        float c0 = bf2f((ushort)(bw[i] & 0xffffu));
        float c1 = bf2f((ushort)(bw[i] >> 16));
        float h0 = fmaxf(a0 + c0 + b1v[o + 2 * i], 0.f);
        float h1 = fmaxf(a1 + c1 + b1v[o + 2 * i + 1], 0.f);
        r += h0 * w2v[o + 2 * i] + h1 * w2v[o + 2 * i + 1];
    }
    return r;
}

__global__ __launch_bounds__(256) void k_moves(const int* __restrict__ srcs,
                                               const int* __restrict__ tgts,
                                               const int* __restrict__ batch,
                                               const ushort* __restrict__ P,
                                               const float* __restrict__ b1,
                                               const float* __restrict__ W2,
                                               const float* __restrict__ b2,
                                               float* __restrict__ logits,
                                               int* __restrict__ mb,
                                               float* __restrict__ pmax,
                                               float* __restrict__ psum) {
    __shared__ unsigned lmax[NGRAPHS];
    __shared__ float lsum[NGRAPHS];
    int tid = threadIdx.x;
    int lane = tid & 63;
    int sub = lane >> 4;
    int ch = lane & 15;
    lmax[tid] = 0u; lmax[tid + 256] = 0u;
    lsum[tid] = 0.f; lsum[tid + 256] = 0.f;
    __syncthreads();

    float b1v[16], w2v[16];
    const float4* b1p = reinterpret_cast<const float4*>(b1);
    const float4* w2p = reinterpret_cast<const float4*>(W2);
#pragma unroll
    for (int q = 0; q < 4; ++q) {
        float4 bv = b1p[ch * 4 + q];
        float4 wv = w2p[ch * 4 + q];
        b1v[q * 4 + 0] = bv.x; b1v[q * 4 + 1] = bv.y; b1v[q * 4 + 2] = bv.z; b1v[q * 4 + 3] = bv.w;
        w2v[q * 4 + 0] = wv.x; w2v[q * 4 + 1] = wv.y; w2v[q * 4 + 2] = wv.z; w2v[q * 4 + 3] = wv.w;
    }
    float b2s = b2[0];

    int wid = (blockIdx.x * 256 + tid) >> 6;
    int nw = (gridDim.x * 256) >> 6;   // 8192 waves

    // ---- Phase A: compute logits; inline LDS atomicMax ----
    for (int base = wid * 8; base < NMOVES; base += nw * 8) {
        int m0 = base + sub;
        int m1 = base + 4 + sub;
        int s0 = srcs[m0], t0 = tgts[m0];
        int s1 = srcs[m1], t1 = tgts[m1];
        const uint4* pa0 = reinterpret_cast<const uint4*>(P + (size_t)s0 * 512 + ch * 16);
        const uint4* pb0 = reinterpret_cast<const uint4*>(P + (size_t)t0 * 512 + 256 + ch * 16);
        const uint4* pa1 = reinterpret_cast<const uint4*>(P + (size_t)s1 * 512 + ch * 16);
        const uint4* pb1 = reinterpret_cast<const uint4*>(P + (size_t)t1 * 512 + 256 + ch * 16);
        uint4 a00 = pa0[0], a01 = pa0[1];
        uint4 c00 = pb0[0], c01 = pb0[1];
        uint4 a10 = pa1[0], a11 = pa1[1];
        uint4 c10 = pb1[0], c11 = pb1[1];
        int g0 = batch[s0];
        int g1 = batch[s1];

        float p0 = dot8(a00, c00, b1v, w2v, 0) + dot8(a01, c01, b1v, w2v, 8);
        float p1 = dot8(a10, c10, b1v, w2v, 0) + dot8(a11, c11, b1v, w2v, 8);
#pragma unroll
        for (int off = 1; off < 16; off <<= 1) {
            p0 += __shfl_xor(p0, off);
            p1 += __shfl_xor(p1, off);
        }
        if (ch == 0) {
            float l0 = p0 + b2s;
            float l1 = p1 + b2s;
            logits[m0] = l0; mb[m0] = g0; atomicMax(&lmax[g0], encf(l0));
            logits[m1] = l1; mb[m1] = g1; atomicMax(&lmax[g1], encf(l1));
        }
    }
    __syncthreads();   // all block-local maxima in lmax

    // ---- Phase B: each lane re-reads one of the wave's 64 moves (L2-hot) ----
    {
        int m = wid * 8 + (lane >> 3) * (nw * 8) + (lane & 7);
        if (m < NMOVES) {
            float l = logits[m];
            int g = mb[m];
            atomicAdd(&lsum[g], __expf(l - decf(lmax[g])));
        }
    }
    __syncthreads();

    // ---- flush block partials (coalesced 2KB rows) ----
#pragma unroll
    for (int i = 0; i < 2; ++i) {
        int s = tid + i * 256;
        unsigned e = lmax[s];
        pmax[(size_t)blockIdx.x * NGRAPHS + s] = (e == 0u) ? -INFINITY : decf(e);
        psum[(size_t)blockIdx.x * NGRAPHS + s] = lsum[s];
    }
}

// ---- fold PBM partials per segment: one block per segment ----
__global__ __launch_bounds__(256) void k_combine(const float* __restrict__ pmax,
                                                 const float* __restrict__ psum,
                                                 float* __restrict__ gmax,
                                                 float* __restrict__ ginv) {
    __shared__ float wred[8];
    int s = blockIdx.x;      // segment 0..511
    int tid = threadIdx.x;   // 0..255
    int lane = tid & 63;
    int wave = tid >> 6;

    float pm[8], ps[8];
#pragma unroll
    for (int i = 0; i < 8; ++i) {
        pm[i] = pmax[(size_t)(tid + 256 * i) * NGRAPHS + s];
        ps[i] = psum[(size_t)(tid + 256 * i) * NGRAPHS + s];
    }
    float M = pm[0];
#pragma unroll
    for (int i = 1; i < 8; ++i) M = fmaxf(M, pm[i]);
#pragma unroll
    for (int off = 32; off; off >>= 1) M = fmaxf(M, __shfl_xor(M, off));
    if (lane == 0) wred[wave] = M;
    __syncthreads();
    M = fmaxf(fmaxf(wred[0], wred[1]), fmaxf(wred[2], wred[3]));

    float S = 0.f;
#pragma unroll
    for (int i = 0; i < 8; ++i)
        if (ps[i] > 0.f) S += ps[i] * __expf(pm[i] - M);
#pragma unroll
    for (int off = 32; off; off >>= 1) S += __shfl_xor(S, off);
    if (lane == 0) wred[4 + wave] = S;
    __syncthreads();
    if (tid == 0) {
        S = wred[4] + wred[5] + wred[6] + wred[7];
        gmax[s] = M;
        ginv[s] = 1.f / (S + 1e-16f);
    }
}

// ---- normalize (vectorized 4 moves/thread) ----
__global__ void k_norm(const float* __restrict__ logits, const int* __restrict__ mb,
                       const float* __restrict__ gmax, const float* __restrict__ ginv,
                       float* __restrict__ out) {
    const int NV = NMOVES / 4;
    int i = blockIdx.x * blockDim.x + threadIdx.x;
    int n = gridDim.x * blockDim.x;
    for (int v = i; v < NV; v += n) {
        float4 l = reinterpret_cast<const float4*>(logits)[v];
        int4 g = reinterpret_cast<const int4*>(mb)[v];
        float4 o;
        o.x = __expf(l.x - gmax[g.x]) * ginv[g.x];
        o.y = __expf(l.y - gmax[g.y]) * ginv[g.y];
        o.z = __expf(l.z - gmax[g.z]) * ginv[g.z];
        o.w = __expf(l.w - gmax[g.w]) * ginv[g.w];
        reinterpret_cast<float4*>(out)[v] = o;
    }
}

extern "C" void kernel_launch(void* const* d_in, const int* in_sizes, int n_in,
                              void* d_out, int out_size, void* d_ws, size_t ws_size,
                              hipStream_t stream) {
    const float* emb = (const float*)d_in[0];
    const int* moves = (const int*)d_in[1];
    const int* batch = (const int*)d_in[2];
    const float* W1 = (const float*)d_in[3];
    const float* b1 = (const float*)d_in[4];
    const float* W2 = (const float*)d_in[5];
    const float* b2 = (const float*)d_in[6];
    float* out = (float*)d_out;

    auto al = [](size_t x) { return (x + 255) & ~(size_t)255; };
    char* ws = (char*)d_ws;
    size_t off = 0;
    ushort* W1t = (ushort*)(ws + off); off += al((size_t)512 * 256 * 2);
    ushort* P   = (ushort*)(ws + off); off += al((size_t)NNODES * 512 * 2);
    float* logits = (float*)(ws + off); off += al((size_t)NMOVES * 4);
    int* mb       = (int*)(ws + off);   off += al((size_t)NMOVES * 4);
    float* pmax   = (float*)(ws + off); off += al((size_t)PBM * NGRAPHS * 4);
    float* psum   = (float*)(ws + off); off += al((size_t)PBM * NGRAPHS * 4);
    float* gmax   = (float*)(ws + off); off += al((size_t)NGRAPHS * 4);
    float* ginv   = (float*)(ws + off); off += al((size_t)NGRAPHS * 4);

    k_convert_w1<<<512, 256, 0, stream>>>(W1, W1t);

    int tiles_m = (NNODES + BM - 1) / BM;   // 782
    k_gemm<<<tiles_m, 512, 0, stream>>>(emb, W1t, P, NNODES);

    k_moves<<<PBM, 256, 0, stream>>>(moves, moves + NMOVES, batch, P, b1, W2, b2,
                                     logits, mb, pmax, psum);
    k_combine<<<NGRAPHS, 256, 0, stream>>>(pmax, psum, gmax, ginv);
    k_norm<<<512, 256, 0, stream>>>(logits, mb, gmax, ginv, out);
}

// Round 15
// 152.084 us; speedup vs baseline: 2.3860x; 1.0087x over previous
//
#include <hip/hip_runtime.h>
#include <hip/hip_bf16.h>

#define NNODES 100000
#define HID 256
#define NMOVES 500000
#define NGRAPHS 512
#define BMG 64     // gemm M-tile (R15: halved, 256-thr blocks, 4 blocks/CU)
#define BN 32
#define PBM 2048   // partial blocks = k_moves grid

typedef __attribute__((ext_vector_type(8))) short short8;
typedef __attribute__((ext_vector_type(4))) float f32x4;

#define AS_GLOBAL __attribute__((address_space(1)))
#define AS_LDS __attribute__((address_space(3)))

__device__ __forceinline__ unsigned f2bf(float f) {
    unsigned u = __builtin_bit_cast(unsigned, f);
    u += 0x7FFFu + ((u >> 16) & 1u);   // round-to-nearest-even
    return u >> 16;
}
__device__ __forceinline__ float bf2f(ushort h) {
    unsigned u = ((unsigned)h) << 16;
    return __builtin_bit_cast(float, u);
}
// order-preserving float<->uint encoding for max
__device__ __forceinline__ unsigned encf(float f) {
    unsigned b = __builtin_bit_cast(unsigned, f);
    return (b & 0x80000000u) ? ~b : (b ^ 0x80000000u);
}
__device__ __forceinline__ float decf(unsigned u) {
    unsigned b = (u & 0x80000000u) ? (u ^ 0x80000000u) : ~u;
    return __builtin_bit_cast(float, b);
}

// ---- build W1' transposed: W1t[n][k] ----
__global__ void k_convert_w1(const float* __restrict__ W1, ushort* __restrict__ W1t) {
    int t = blockIdx.x * blockDim.x + threadIdx.x; // 131072
    int n = t >> 8, k = t & 255;
    float v = (n < 256) ? W1[k * 256 + n] : W1[(k + 256) * 256 + (n - 256)];
    W1t[t] = (ushort)f2bf(v);
}

// ---- GEMM: R9 per-wave structure, BM=64 / 256-thr blocks / 32KB LDS ----
// Same wave tile (af[2][8], 16 MFMA + 8 ds_read + 8 stores per strip) as the
// proven 82us config; only the block granularity changes: 4 blocks/CU instead
// of 2, so barrier stalls of one block hide under compute of the others.
__global__ __launch_bounds__(256, 4) void k_gemm(const float* __restrict__ emb,
                                                 const ushort* __restrict__ Bt,
                                                 ushort* __restrict__ P, int M) {
    __shared__ __align__(16) char lds[32768];   // A 64x256 staged, then 2x16KB B
    int tid = threadIdx.x;
    int lane = tid & 63;
    int wave = tid >> 6;   // 0..3
    int tm = blockIdx.x * BMG;
    int wm = wave >> 1;    // 0..1  (32-row group)
    int wn = wave & 1;     // 0..1  (16-col group within strip)
    int fr = lane & 15;
    int q = lane >> 4;     // 0..3
    int sw = fr & 7;

    // ---- Phase 1: stage A 64x256 (f32->bf16, swizzled ds_write) ----
#pragma unroll
    for (int i = 0; i < 8; ++i) {
        int cid = i * 256 + tid;         // 16B-bf16 chunk id, 0..2047
        int row = cid >> 5;              // 0..63
        int j = cid & 31;
        int grow = tm + row; if (grow >= M) grow = M - 1;
        const float4* sp = reinterpret_cast<const float4*>(emb + (size_t)grow * 256 + (j << 3));
        float4 v0 = sp[0], v1 = sp[1];
        uint4 o;
        o.x = f2bf(v0.x) | (f2bf(v0.y) << 16);
        o.y = f2bf(v0.z) | (f2bf(v0.w) << 16);
        o.z = f2bf(v1.x) | (f2bf(v1.y) << 16);
        o.w = f2bf(v1.z) | (f2bf(v1.w) << 16);
        *reinterpret_cast<uint4*>(lds + row * 512 + ((j ^ (row & 7)) << 4)) = o;
    }
    __syncthreads();

    // ---- Phase 2: A fragments -> registers (16 x short8) ----
    short8 af[2][8];
#pragma unroll
    for (int m = 0; m < 2; ++m) {
        int row = wm * 32 + m * 16 + fr;
#pragma unroll
        for (int kt = 0; kt < 8; ++kt)
            af[m][kt] = *reinterpret_cast<const short8*>(
                lds + row * 512 + (((kt * 4 + q) ^ sw) << 4));
    }
    __syncthreads();   // all waves extracted; lds region now free for B

    // ---- Phase 3: 16 B strips (BN=32), double-buffered, counted vmcnt ----
#define STAGE(STRIP, BUFI)                                                          \
    {                                                                               \
        _Pragma("unroll")                                                           \
        for (int i = 0; i < 4; ++i) {                                               \
            int cid = i * 256 + tid;       /* 16B chunk 0..1023 */                  \
            int row = cid >> 5, c = cid & 31;                                       \
            const ushort* src = Bt + (size_t)((STRIP) * BN + row) * 256             \
                                   + ((c ^ (row & 7)) << 3);                        \
            __builtin_amdgcn_global_load_lds((const AS_GLOBAL void*)src,            \
                (AS_LDS void*)(lds + (BUFI) * 16384 + cid * 16), 16, 0, 0);         \
        }                                                                           \
    }

    STAGE(0, 0);
    STAGE(1, 1);

#pragma unroll 1
    for (int r = 0; r < 16; ++r) {
        // FIFO at wait(r): [stage(r)(4), stores(r-1)(8), stage(r+1)(4)]
        if (r == 0)      asm volatile("s_waitcnt vmcnt(4)" ::: "memory");
        else if (r < 15) asm volatile("s_waitcnt vmcnt(12)" ::: "memory");
        else             asm volatile("s_waitcnt vmcnt(8)" ::: "memory");
        asm volatile("s_barrier" ::: "memory");

        const char* bp = lds + (r & 1) * 16384;
        f32x4 acc0 = {0.f, 0.f, 0.f, 0.f};
        f32x4 acc1 = {0.f, 0.f, 0.f, 0.f};
#pragma unroll
        for (int kt = 0; kt < 8; ++kt) {
            short8 bf = *reinterpret_cast<const short8*>(
                bp + (wn * 16 + fr) * 512 + (((kt * 4 + q) ^ sw) << 4));
            acc0 = __builtin_amdgcn_mfma_f32_16x16x32_bf16(af[0][kt], bf, acc0, 0, 0, 0);
            acc1 = __builtin_amdgcn_mfma_f32_16x16x32_bf16(af[1][kt], bf, acc1, 0, 0, 0);
        }
        // epilogue: lane = P-col (fr), rows q*4+j; 8 ushort stores, 32B sectors
        int pcol = r * BN + wn * 16 + fr;
#pragma unroll
        for (int j = 0; j < 4; ++j) {
            int prow0 = tm + wm * 32 + q * 4 + j;
            if (prow0 < M) P[(size_t)prow0 * 512 + pcol] = (ushort)f2bf(acc0[j]);
            int prow1 = prow0 + 16;
            if (prow1 < M) P[(size_t)prow1 * 512 + pcol] = (ushort)f2bf(acc1[j]);
        }

        asm volatile("s_barrier" ::: "memory");
        if (r < 14) STAGE(r + 2, (r & 1));
    }
#undef STAGE
}

// ---- per-move MLP tail + FUSED segment partials ----
__device__ __forceinline__ float dot8(uint4 a, uint4 b, const float* b1v, const float* w2v, int o) {
    unsigned aw[4] = {a.x, a.y, a.z, a.w};
    unsigned bw[4] = {b.x, b.y, b.z, b.w};
    float r = 0.f;
#pragma unroll
    for (int i = 0; i < 4; ++i) {
        float a0 = bf2f((ushort)(aw[i] & 0xffffu));
        float a1 = bf2f((ushort)(aw[i] >> 16));
        float c0 = bf2f((ushort)(bw[i] & 0xffffu));
        float c1 = bf2f((ushort)(bw[i] >> 16));
        float h0 = fmaxf(a0 + c0 + b1v[o + 2 * i], 0.f);
        float h1 = fmaxf(a1 + c1 + b1v[o + 2 * i + 1], 0.f);
        r += h0 * w2v[o + 2 * i] + h1 * w2v[o + 2 * i + 1];
    }
    return r;
}

__global__ __launch_bounds__(256) void k_moves(const int* __restrict__ srcs,
                                               const int* __restrict__ tgts,
                                               const int* __restrict__ batch,
                                               const ushort* __restrict__ P,
                                               const float* __restrict__ b1,
                                               const float* __restrict__ W2,
                                               const float* __restrict__ b2,
                                               float* __restrict__ logits,
                                               int* __restrict__ mb,
                                               float* __restrict__ pmax,
                                               float* __restrict__ psum) {
    __shared__ unsigned lmax[NGRAPHS];
    __shared__ float lsum[NGRAPHS];
    int tid = threadIdx.x;
    int lane = tid & 63;
    int sub = lane >> 4;
    int ch = lane & 15;
    lmax[tid] = 0u; lmax[tid + 256] = 0u;
    lsum[tid] = 0.f; lsum[tid + 256] = 0.f;
    __syncthreads();

    float b1v[16], w2v[16];
    const float4* b1p = reinterpret_cast<const float4*>(b1);
    const float4* w2p = reinterpret_cast<const float4*>(W2);
#pragma unroll
    for (int q = 0; q < 4; ++q) {
        float4 bv = b1p[ch * 4 + q];
        float4 wv = w2p[ch * 4 + q];
        b1v[q * 4 + 0] = bv.x; b1v[q * 4 + 1] = bv.y; b1v[q * 4 + 2] = bv.z; b1v[q * 4 + 3] = bv.w;
        w2v[q * 4 + 0] = wv.x; w2v[q * 4 + 1] = wv.y; w2v[q * 4 + 2] = wv.z; w2v[q * 4 + 3] = wv.w;
    }
    float b2s = b2[0];

    int wid = (blockIdx.x * 256 + tid) >> 6;
    int nw = (gridDim.x * 256) >> 6;   // 8192 waves

    // ---- Phase A: compute logits; inline LDS atomicMax ----
    for (int base = wid * 8; base < NMOVES; base += nw * 8) {
        int m0 = base + sub;
        int m1 = base + 4 + sub;
        int s0 = srcs[m0], t0 = tgts[m0];
        int s1 = srcs[m1], t1 = tgts[m1];
        const uint4* pa0 = reinterpret_cast<const uint4*>(P + (size_t)s0 * 512 + ch * 16);
        const uint4* pb0 = reinterpret_cast<const uint4*>(P + (size_t)t0 * 512 + 256 + ch * 16);
        const uint4* pa1 = reinterpret_cast<const uint4*>(P + (size_t)s1 * 512 + ch * 16);
        const uint4* pb1 = reinterpret_cast<const uint4*>(P + (size_t)t1 * 512 + 256 + ch * 16);
        uint4 a00 = pa0[0], a01 = pa0[1];
        uint4 c00 = pb0[0], c01 = pb0[1];
        uint4 a10 = pa1[0], a11 = pa1[1];
        uint4 c10 = pb1[0], c11 = pb1[1];
        int g0 = batch[s0];
        int g1 = batch[s1];

        float p0 = dot8(a00, c00, b1v, w2v, 0) + dot8(a01, c01, b1v, w2v, 8);
        float p1 = dot8(a10, c10, b1v, w2v, 0) + dot8(a11, c11, b1v, w2v, 8);
#pragma unroll
        for (int off = 1; off < 16; off <<= 1) {
            p0 += __shfl_xor(p0, off);
            p1 += __shfl_xor(p1, off);
        }
        if (ch == 0) {
            float l0 = p0 + b2s;
            float l1 = p1 + b2s;
            logits[m0] = l0; mb[m0] = g0; atomicMax(&lmax[g0], encf(l0));
            logits[m1] = l1; mb[m1] = g1; atomicMax(&lmax[g1], encf(l1));
        }
    }
    __syncthreads();   // all block-local maxima in lmax

    // ---- Phase B: each lane re-reads one of the wave's 64 moves (L2-hot) ----
    {
        int m = wid * 8 + (lane >> 3) * (nw * 8) + (lane & 7);
        if (m < NMOVES) {
            float l = logits[m];
            int g = mb[m];
            atomicAdd(&lsum[g], __expf(l - decf(lmax[g])));
        }
    }
    __syncthreads();

    // ---- flush block partials (coalesced 2KB rows) ----
#pragma unroll
    for (int i = 0; i < 2; ++i) {
        int s = tid + i * 256;
        unsigned e = lmax[s];
        pmax[(size_t)blockIdx.x * NGRAPHS + s] = (e == 0u) ? -INFINITY : decf(e);
        psum[(size_t)blockIdx.x * NGRAPHS + s] = lsum[s];
    }
}

// ---- fold PBM partials per segment: one block per segment ----
__global__ __launch_bounds__(256) void k_combine(const float* __restrict__ pmax,
                                                 const float* __restrict__ psum,
                                                 float* __restrict__ gmax,
                                                 float* __restrict__ ginv) {
    __shared__ float wred[8];
    int s = blockIdx.x;      // segment 0..511
    int tid = threadIdx.x;   // 0..255
    int lane = tid & 63;
    int wave = tid >> 6;

    float pm[8], ps[8];
#pragma unroll
    for (int i = 0; i < 8; ++i) {
        pm[i] = pmax[(size_t)(tid + 256 * i) * NGRAPHS + s];
        ps[i] = psum[(size_t)(tid + 256 * i) * NGRAPHS + s];
    }
    float M = pm[0];
#pragma unroll
    for (int i = 1; i < 8; ++i) M = fmaxf(M, pm[i]);
#pragma unroll
    for (int off = 32; off; off >>= 1) M = fmaxf(M, __shfl_xor(M, off));
    if (lane == 0) wred[wave] = M;
    __syncthreads();
    M = fmaxf(fmaxf(wred[0], wred[1]), fmaxf(wred[2], wred[3]));

    float S = 0.f;
#pragma unroll
    for (int i = 0; i < 8; ++i)
        if (ps[i] > 0.f) S += ps[i] * __expf(pm[i] - M);
#pragma unroll
    for (int off = 32; off; off >>= 1) S += __shfl_xor(S, off);
    if (lane == 0) wred[4 + wave] = S;
    __syncthreads();
    if (tid == 0) {
        S = wred[4] + wred[5] + wred[6] + wred[7];
        gmax[s] = M;
        ginv[s] = 1.f / (S + 1e-16f);
    }
}

// ---- normalize (vectorized 4 moves/thread) ----
__global__ void k_norm(const float* __restrict__ logits, const int* __restrict__ mb,
                       const float* __restrict__ gmax, const float* __restrict__ ginv,
                       float* __restrict__ out) {
    const int NV = NMOVES / 4;
    int i = blockIdx.x * blockDim.x + threadIdx.x;
    int n = gridDim.x * blockDim.x;
    for (int v = i; v < NV; v += n) {
        float4 l = reinterpret_cast<const float4*>(logits)[v];
        int4 g = reinterpret_cast<const int4*>(mb)[v];
        float4 o;
        o.x = __expf(l.x - gmax[g.x]) * ginv[g.x];
        o.y = __expf(l.y - gmax[g.y]) * ginv[g.y];
        o.z = __expf(l.z - gmax[g.z]) * ginv[g.z];
        o.w = __expf(l.w - gmax[g.w]) * ginv[g.w];
        reinterpret_cast<float4*>(out)[v] = o;
    }
}

extern "C" void kernel_launch(void* const* d_in, const int* in_sizes, int n_in,
                              void* d_out, int out_size, void* d_ws, size_t ws_size,
                              hipStream_t stream) {
    const float* emb = (const float*)d_in[0];
    const int* moves = (const int*)d_in[1];
    const int* batch = (const int*)d_in[2];
    const float* W1 = (const float*)d_in[3];
    const float* b1 = (const float*)d_in[4];
    const float* W2 = (const float*)d_in[5];
    const float* b2 = (const float*)d_in[6];
    float* out = (float*)d_out;

    auto al = [](size_t x) { return (x + 255) & ~(size_t)255; };
    char* ws = (char*)d_ws;
    size_t off = 0;
    ushort* W1t = (ushort*)(ws + off); off += al((size_t)512 * 256 * 2);
    ushort* P   = (ushort*)(ws + off); off += al((size_t)NNODES * 512 * 2);
    float* logits = (float*)(ws + off); off += al((size_t)NMOVES * 4);
    int* mb       = (int*)(ws + off);   off += al((size_t)NMOVES * 4);
    float* pmax   = (float*)(ws + off); off += al((size_t)PBM * NGRAPHS * 4);
    float* psum   = (float*)(ws + off); off += al((size_t)PBM * NGRAPHS * 4);
    float* gmax   = (float*)(ws + off); off += al((size_t)NGRAPHS * 4);
    float* ginv   = (float*)(ws + off); off += al((size_t)NGRAPHS * 4);

    k_convert_w1<<<512, 256, 0, stream>>>(W1, W1t);

    int tiles_m = (NNODES + BMG - 1) / BMG;   // 1563
    k_gemm<<<tiles_m, 256, 0, stream>>>(emb, W1t, P, NNODES);

    k_moves<<<PBM, 256, 0, stream>>>(moves, moves + NMOVES, batch, P, b1, W2, b2,
                                     logits, mb, pmax, psum);
    k_combine<<<NGRAPHS, 256, 0, stream>>>(pmax, psum, gmax, ginv);
    k_norm<<<512, 256, 0, stream>>>(logits, mb, gmax, ginv, out);
}

// Round 16
// 151.550 us; speedup vs baseline: 2.3944x; 1.0035x over previous
//
#include <hip/hip_runtime.h>
#include <hip/hip_bf16.h>

#define NNODES 100000
#define HID 256
#define NMOVES 500000
#define NGRAPHS 512
#define BMG 64     // gemm M-tile
#define BN 32
#define PBM 2048   // partial blocks = k_moves grid

typedef __attribute__((ext_vector_type(8))) short short8;
typedef __attribute__((ext_vector_type(4))) float f32x4;

#define AS_GLOBAL __attribute__((address_space(1)))
#define AS_LDS __attribute__((address_space(3)))

__device__ __forceinline__ unsigned f2bf(float f) {
    unsigned u = __builtin_bit_cast(unsigned, f);
    u += 0x7FFFu + ((u >> 16) & 1u);   // round-to-nearest-even
    return u >> 16;
}
__device__ __forceinline__ float bf2f(ushort h) {
    unsigned u = ((unsigned)h) << 16;
    return __builtin_bit_cast(float, u);
}
// order-preserving float<->uint encoding for max
__device__ __forceinline__ unsigned encf(float f) {
    unsigned b = __builtin_bit_cast(unsigned, f);
    return (b & 0x80000000u) ? ~b : (b ^ 0x80000000u);
}
__device__ __forceinline__ float decf(unsigned u) {
    unsigned b = (u & 0x80000000u) ? (u ^ 0x80000000u) : ~u;
    return __builtin_bit_cast(float, b);
}

// ---- build W1' transposed: W1t[n][k] ----
__global__ void k_convert_w1(const float* __restrict__ W1, ushort* __restrict__ W1t) {
    int t = blockIdx.x * blockDim.x + threadIdx.x; // 131072
    int n = t >> 8, k = t & 255;
    float v = (n < 256) ? W1[k * 256 + n] : W1[(k + 256) * 256 + (n - 256)];
    W1t[t] = (ushort)f2bf(v);
}

// ---- GEMM: unchanged from R15 (82us; invariant to 5 restructures) ----
__global__ __launch_bounds__(256, 4) void k_gemm(const float* __restrict__ emb,
                                                 const ushort* __restrict__ Bt,
                                                 ushort* __restrict__ P, int M) {
    __shared__ __align__(16) char lds[32768];
    int tid = threadIdx.x;
    int lane = tid & 63;
    int wave = tid >> 6;   // 0..3
    int tm = blockIdx.x * BMG;
    int wm = wave >> 1;    // 0..1
    int wn = wave & 1;     // 0..1
    int fr = lane & 15;
    int q = lane >> 4;     // 0..3
    int sw = fr & 7;

#pragma unroll
    for (int i = 0; i < 8; ++i) {
        int cid = i * 256 + tid;
        int row = cid >> 5;
        int j = cid & 31;
        int grow = tm + row; if (grow >= M) grow = M - 1;
        const float4* sp = reinterpret_cast<const float4*>(emb + (size_t)grow * 256 + (j << 3));
        float4 v0 = sp[0], v1 = sp[1];
        uint4 o;
        o.x = f2bf(v0.x) | (f2bf(v0.y) << 16);
        o.y = f2bf(v0.z) | (f2bf(v0.w) << 16);
        o.z = f2bf(v1.x) | (f2bf(v1.y) << 16);
        o.w = f2bf(v1.z) | (f2bf(v1.w) << 16);
        *reinterpret_cast<uint4*>(lds + row * 512 + ((j ^ (row & 7)) << 4)) = o;
    }
    __syncthreads();

    short8 af[2][8];
#pragma unroll
    for (int m = 0; m < 2; ++m) {
        int row = wm * 32 + m * 16 + fr;
#pragma unroll
        for (int kt = 0; kt < 8; ++kt)
            af[m][kt] = *reinterpret_cast<const short8*>(
                lds + row * 512 + (((kt * 4 + q) ^ sw) << 4));
    }
    __syncthreads();

#define STAGE(STRIP, BUFI)                                                          \
    {                                                                               \
        _Pragma("unroll")                                                           \
        for (int i = 0; i < 4; ++i) {                                               \
            int cid = i * 256 + tid;                                                \
            int row = cid >> 5, c = cid & 31;                                       \
            const ushort* src = Bt + (size_t)((STRIP) * BN + row) * 256             \
                                   + ((c ^ (row & 7)) << 3);                        \
            __builtin_amdgcn_global_load_lds((const AS_GLOBAL void*)src,            \
                (AS_LDS void*)(lds + (BUFI) * 16384 + cid * 16), 16, 0, 0);         \
        }                                                                           \
    }

    STAGE(0, 0);
    STAGE(1, 1);

#pragma unroll 1
    for (int r = 0; r < 16; ++r) {
        if (r == 0)      asm volatile("s_waitcnt vmcnt(4)" ::: "memory");
        else if (r < 15) asm volatile("s_waitcnt vmcnt(12)" ::: "memory");
        else             asm volatile("s_waitcnt vmcnt(8)" ::: "memory");
        asm volatile("s_barrier" ::: "memory");

        const char* bp = lds + (r & 1) * 16384;
        f32x4 acc0 = {0.f, 0.f, 0.f, 0.f};
        f32x4 acc1 = {0.f, 0.f, 0.f, 0.f};
#pragma unroll
        for (int kt = 0; kt < 8; ++kt) {
            short8 bf = *reinterpret_cast<const short8*>(
                bp + (wn * 16 + fr) * 512 + (((kt * 4 + q) ^ sw) << 4));
            acc0 = __builtin_amdgcn_mfma_f32_16x16x32_bf16(af[0][kt], bf, acc0, 0, 0, 0);
            acc1 = __builtin_amdgcn_mfma_f32_16x16x32_bf16(af[1][kt], bf, acc1, 0, 0, 0);
        }
        int pcol = r * BN + wn * 16 + fr;
#pragma unroll
        for (int j = 0; j < 4; ++j) {
            int prow0 = tm + wm * 32 + q * 4 + j;
            if (prow0 < M) P[(size_t)prow0 * 512 + pcol] = (ushort)f2bf(acc0[j]);
            int prow1 = prow0 + 16;
            if (prow1 < M) P[(size_t)prow1 * 512 + pcol] = (ushort)f2bf(acc1[j]);
        }

        asm volatile("s_barrier" ::: "memory");
        if (r < 14) STAGE(r + 2, (r & 1));
    }
#undef STAGE
}

// ---- per-move MLP tail + fused partials; Phase A unrolled x2 (16 moves/wave-iter) ----
__device__ __forceinline__ float dot8(uint4 a, uint4 b, const float* b1v, const float* w2v, int o) {
    unsigned aw[4] = {a.x, a.y, a.z, a.w};
    unsigned bw[4] = {b.x, b.y, b.z, b.w};
    float r = 0.f;
#pragma unroll
    for (int i = 0; i < 4; ++i) {
        float a0 = bf2f((ushort)(aw[i] & 0xffffu));
        float a1 = bf2f((ushort)(aw[i] >> 16));
        float c0 = bf2f((ushort)(bw[i] & 0xffffu));
        float c1 = bf2f((ushort)(bw[i] >> 16));
        float h0 = fmaxf(a0 + c0 + b1v[o + 2 * i], 0.f);
        float h1 = fmaxf(a1 + c1 + b1v[o + 2 * i + 1], 0.f);
        r += h0 * w2v[o + 2 * i] + h1 * w2v[o + 2 * i + 1];
    }
    return r;
}

__global__ __launch_bounds__(256) void k_moves(const int* __restrict__ srcs,
                                               const int* __restrict__ tgts,
                                               const int* __restrict__ batch,
                                               const ushort* __restrict__ P,
                                               const float* __restrict__ b1,
                                               const float* __restrict__ W2,
                                               const float* __restrict__ b2,
                                               float* __restrict__ logits,
                                               int* __restrict__ mb,
                                               float* __restrict__ pmax,
                                               float* __restrict__ psum) {
    __shared__ unsigned lmax[NGRAPHS];
    __shared__ float lsum[NGRAPHS];
    int tid = threadIdx.x;
    int lane = tid & 63;
    int sub = lane >> 4;
    int ch = lane & 15;
    lmax[tid] = 0u; lmax[tid + 256] = 0u;
    lsum[tid] = 0.f; lsum[tid + 256] = 0.f;
    __syncthreads();

    float b1v[16], w2v[16];
    const float4* b1p = reinterpret_cast<const float4*>(b1);
    const float4* w2p = reinterpret_cast<const float4*>(W2);
#pragma unroll
    for (int q = 0; q < 4; ++q) {
        float4 bv = b1p[ch * 4 + q];
        float4 wv = w2p[ch * 4 + q];
        b1v[q * 4 + 0] = bv.x; b1v[q * 4 + 1] = bv.y; b1v[q * 4 + 2] = bv.z; b1v[q * 4 + 3] = bv.w;
        w2v[q * 4 + 0] = wv.x; w2v[q * 4 + 1] = wv.y; w2v[q * 4 + 2] = wv.z; w2v[q * 4 + 3] = wv.w;
    }
    float b2s = b2[0];

    int wid = (blockIdx.x * 256 + tid) >> 6;
    int nw = (gridDim.x * 256) >> 6;   // 8192 waves

    // ---- Phase A: 16 moves per wave-iter; 16x16B gathers in flight/lane ----
    for (int base = wid * 16; base < NMOVES; base += nw * 16) {
        int m0 = base + sub;
        int m1 = base + 4 + sub;
        int m2 = base + 8 + sub;
        int m3 = base + 12 + sub;
        int s0 = srcs[m0], t0 = tgts[m0];
        int s1 = srcs[m1], t1 = tgts[m1];
        int s2 = srcs[m2], t2 = tgts[m2];
        int s3 = srcs[m3], t3 = tgts[m3];
        const uint4* pa0 = reinterpret_cast<const uint4*>(P + (size_t)s0 * 512 + ch * 16);
        const uint4* pb0 = reinterpret_cast<const uint4*>(P + (size_t)t0 * 512 + 256 + ch * 16);
        const uint4* pa1 = reinterpret_cast<const uint4*>(P + (size_t)s1 * 512 + ch * 16);
        const uint4* pb1 = reinterpret_cast<const uint4*>(P + (size_t)t1 * 512 + 256 + ch * 16);
        const uint4* pa2 = reinterpret_cast<const uint4*>(P + (size_t)s2 * 512 + ch * 16);
        const uint4* pb2 = reinterpret_cast<const uint4*>(P + (size_t)t2 * 512 + 256 + ch * 16);
        const uint4* pa3 = reinterpret_cast<const uint4*>(P + (size_t)s3 * 512 + ch * 16);
        const uint4* pb3 = reinterpret_cast<const uint4*>(P + (size_t)t3 * 512 + 256 + ch * 16);
        uint4 a00 = pa0[0], a01 = pa0[1];
        uint4 c00 = pb0[0], c01 = pb0[1];
        uint4 a10 = pa1[0], a11 = pa1[1];
        uint4 c10 = pb1[0], c11 = pb1[1];
        uint4 a20 = pa2[0], a21 = pa2[1];
        uint4 c20 = pb2[0], c21 = pb2[1];
        uint4 a30 = pa3[0], a31 = pa3[1];
        uint4 c30 = pb3[0], c31 = pb3[1];
        int g0 = batch[s0];
        int g1 = batch[s1];
        int g2 = batch[s2];
        int g3 = batch[s3];

        float p0 = dot8(a00, c00, b1v, w2v, 0) + dot8(a01, c01, b1v, w2v, 8);
        float p1 = dot8(a10, c10, b1v, w2v, 0) + dot8(a11, c11, b1v, w2v, 8);
        float p2 = dot8(a20, c20, b1v, w2v, 0) + dot8(a21, c21, b1v, w2v, 8);
        float p3 = dot8(a30, c30, b1v, w2v, 0) + dot8(a31, c31, b1v, w2v, 8);
#pragma unroll
        for (int off = 1; off < 16; off <<= 1) {
            p0 += __shfl_xor(p0, off);
            p1 += __shfl_xor(p1, off);
            p2 += __shfl_xor(p2, off);
            p3 += __shfl_xor(p3, off);
        }
        if (ch == 0) {
            float l0 = p0 + b2s;
            float l1 = p1 + b2s;
            float l2 = p2 + b2s;
            float l3 = p3 + b2s;
            logits[m0] = l0; mb[m0] = g0; atomicMax(&lmax[g0], encf(l0));
            logits[m1] = l1; mb[m1] = g1; atomicMax(&lmax[g1], encf(l1));
            logits[m2] = l2; mb[m2] = g2; atomicMax(&lmax[g2], encf(l2));
            logits[m3] = l3; mb[m3] = g3; atomicMax(&lmax[g3], encf(l3));
        }
    }
    __syncthreads();

    // ---- Phase B: each lane re-reads one of the wave's 64 moves (L2-hot) ----
    {
        int m = wid * 16 + (lane >> 4) * (nw * 16) + (lane & 15);
        if (m < NMOVES) {
            float l = logits[m];
            int g = mb[m];
            atomicAdd(&lsum[g], __expf(l - decf(lmax[g])));
        }
    }
    __syncthreads();

    // ---- flush block partials (coalesced 2KB rows) ----
#pragma unroll
    for (int i = 0; i < 2; ++i) {
        int s = tid + i * 256;
        unsigned e = lmax[s];
        pmax[(size_t)blockIdx.x * NGRAPHS + s] = (e == 0u) ? -INFINITY : decf(e);
        psum[(size_t)blockIdx.x * NGRAPHS + s] = lsum[s];
    }
}

// ---- fold PBM partials per segment: one block per segment ----
__global__ __launch_bounds__(256) void k_combine(const float* __restrict__ pmax,
                                                 const float* __restrict__ psum,
                                                 float* __restrict__ gmax,
                                                 float* __restrict__ ginv) {
    __shared__ float wred[8];
    int s = blockIdx.x;      // segment 0..511
    int tid = threadIdx.x;   // 0..255
    int lane = tid & 63;
    int wave = tid >> 6;

    float pm[8], ps[8];
#pragma unroll
    for (int i = 0; i < 8; ++i) {
        pm[i] = pmax[(size_t)(tid + 256 * i) * NGRAPHS + s];
        ps[i] = psum[(size_t)(tid + 256 * i) * NGRAPHS + s];
    }
    float M = pm[0];
#pragma unroll
    for (int i = 1; i < 8; ++i) M = fmaxf(M, pm[i]);
#pragma unroll
    for (int off = 32; off; off >>= 1) M = fmaxf(M, __shfl_xor(M, off));
    if (lane == 0) wred[wave] = M;
    __syncthreads();
    M = fmaxf(fmaxf(wred[0], wred[1]), fmaxf(wred[2], wred[3]));

    float S = 0.f;
#pragma unroll
    for (int i = 0; i < 8; ++i)
        if (ps[i] > 0.f) S += ps[i] * __expf(pm[i] - M);
#pragma unroll
    for (int off = 32; off; off >>= 1) S += __shfl_xor(S, off);
    if (lane == 0) wred[4 + wave] = S;
    __syncthreads();
    if (tid == 0) {
        S = wred[4] + wred[5] + wred[6] + wred[7];
        gmax[s] = M;
        ginv[s] = 1.f / (S + 1e-16f);
    }
}

// ---- normalize (vectorized 4 moves/thread) ----
__global__ void k_norm(const float* __restrict__ logits, const int* __restrict__ mb,
                       const float* __restrict__ gmax, const float* __restrict__ ginv,
                       float* __restrict__ out) {
    const int NV = NMOVES / 4;
    int i = blockIdx.x * blockDim.x + threadIdx.x;
    int n = gridDim.x * blockDim.x;
    for (int v = i; v < NV; v += n) {
        float4 l = reinterpret_cast<const float4*>(logits)[v];
        int4 g = reinterpret_cast<const int4*>(mb)[v];
        float4 o;
        o.x = __expf(l.x - gmax[g.x]) * ginv[g.x];
        o.y = __expf(l.y - gmax[g.y]) * ginv[g.y];
        o.z = __expf(l.z - gmax[g.z]) * ginv[g.z];
        o.w = __expf(l.w - gmax[g.w]) * ginv[g.w];
        reinterpret_cast<float4*>(out)[v] = o;
    }
}

extern "C" void kernel_launch(void* const* d_in, const int* in_sizes, int n_in,
                              void* d_out, int out_size, void* d_ws, size_t ws_size,
                              hipStream_t stream) {
    const float* emb = (const float*)d_in[0];
    const int* moves = (const int*)d_in[1];
    const int* batch = (const int*)d_in[2];
    const float* W1 = (const float*)d_in[3];
    const float* b1 = (const float*)d_in[4];
    const float* W2 = (const float*)d_in[5];
    const float* b2 = (const float*)d_in[6];
    float* out = (float*)d_out;

    auto al = [](size_t x) { return (x + 255) & ~(size_t)255; };
    char* ws = (char*)d_ws;
    size_t off = 0;
    ushort* W1t = (ushort*)(ws + off); off += al((size_t)512 * 256 * 2);
    ushort* P   = (ushort*)(ws + off); off += al((size_t)NNODES * 512 * 2);
    float* logits = (float*)(ws + off); off += al((size_t)NMOVES * 4);
    int* mb       = (int*)(ws + off);   off += al((size_t)NMOVES * 4);
    float* pmax   = (float*)(ws + off); off += al((size_t)PBM * NGRAPHS * 4);
    float* psum   = (float*)(ws + off); off += al((size_t)PBM * NGRAPHS * 4);
    float* gmax   = (float*)(ws + off); off += al((size_t)NGRAPHS * 4);
    float* ginv   = (float*)(ws + off); off += al((size_t)NGRAPHS * 4);

    k_convert_w1<<<512, 256, 0, stream>>>(W1, W1t);

    int tiles_m = (NNODES + BMG - 1) / BMG;   // 1563
    k_gemm<<<tiles_m, 256, 0, stream>>>(emb, W1t, P, NNODES);

    k_moves<<<PBM, 256, 0, stream>>>(moves, moves + NMOVES, batch, P, b1, W2, b2,
                                     logits, mb, pmax, psum);
    k_combine<<<NGRAPHS, 256, 0, stream>>>(pmax, psum, gmax, ginv);
    k_norm<<<512, 256, 0, stream>>>(logits, mb, gmax, ginv, out);
}